// Round 2
// baseline (4864.603 us; speedup 1.0000x reference)
//
#include <hip/hip_runtime.h>
#include <stdint.h>

#define BB 8
#define NN 577
#define DD 768
#define HH 16
#define HD 48
#define CC 32
#define M1 4616   /* B*N  */
#define M2 9232   /* 2*B*N */

static __device__ __forceinline__ float bf_lo(uint32_t u){ return __uint_as_float(u << 16); }
static __device__ __forceinline__ float bf_hi(uint32_t u){ return __uint_as_float(u & 0xffff0000u); }
static __device__ __forceinline__ uint16_t f2bf(float f){
    uint32_t u = __float_as_uint(f);
    return (uint16_t)((u + 0x7fffu + ((u >> 16) & 1u)) >> 16);
}

// 48-term bf16x2 dot product with 4 independent accumulation chains (FMA latency hiding)
static __device__ __forceinline__ float dot48(const uint32_t* qp, const uint32_t* kp) {
    float s0 = 0.f, s1 = 0.f, s2 = 0.f, s3 = 0.f;
#pragma unroll
    for (int dd = 0; dd < 24; dd += 2) {
        uint32_t q0 = qp[dd],     k0 = kp[dd];
        uint32_t q1 = qp[dd + 1], k1 = kp[dd + 1];
        s0 += bf_lo(q0) * bf_lo(k0);
        s1 += bf_hi(q0) * bf_hi(k0);
        s2 += bf_lo(q1) * bf_lo(k1);
        s3 += bf_hi(q1) * bf_hi(k1);
    }
    return (s0 + s1) + (s2 + s3);
}

// ---------------------------------------------------------------------------
// K1: qkv = [x; x_freq] @ qkv_w^T + qkv_b, scattered to bf16 head-layout
//     q/k/v[b][h][n][d].  M=9232, N=2304, K=768.  fp32 tiled GEMM 64x64x16.
// ---------------------------------------------------------------------------
__global__ __launch_bounds__(256) void k_qkv(
    const float* __restrict__ x, const float* __restrict__ xf,
    const float* __restrict__ w, const float* __restrict__ bias,
    uint16_t* __restrict__ qA, uint16_t* __restrict__ kA, uint16_t* __restrict__ vA,
    uint16_t* __restrict__ qF, uint16_t* __restrict__ kF)
{
    __shared__ float As[16][65];
    __shared__ float Bs[16][65];
    const int t    = threadIdx.x;
    const int m0   = blockIdx.x * 64;
    const int n0   = blockIdx.y * 64;
    const int lrow = t >> 2;
    const int lk4  = (t & 3) << 2;
    const int tm   = (t & 15) << 2;
    const int tn   = (t >> 4) << 2;
    float acc[4][4] = {};

    for (int k0 = 0; k0 < DD; k0 += 16) {
        int gm = m0 + lrow;
        float4 av = make_float4(0.f, 0.f, 0.f, 0.f);
        if (gm < M2) {
            const float* src = (gm < M1) ? (x + (size_t)gm * DD) : (xf + (size_t)(gm - M1) * DD);
            av = *reinterpret_cast<const float4*>(src + k0 + lk4);
        }
        As[lk4 + 0][lrow] = av.x; As[lk4 + 1][lrow] = av.y;
        As[lk4 + 2][lrow] = av.z; As[lk4 + 3][lrow] = av.w;
        int gj = n0 + lrow;
        float4 bv = *reinterpret_cast<const float4*>(w + (size_t)gj * DD + k0 + lk4);
        Bs[lk4 + 0][lrow] = bv.x; Bs[lk4 + 1][lrow] = bv.y;
        Bs[lk4 + 2][lrow] = bv.z; Bs[lk4 + 3][lrow] = bv.w;
        __syncthreads();
#pragma unroll
        for (int k = 0; k < 16; ++k) {
            float a[4], b[4];
#pragma unroll
            for (int i = 0; i < 4; ++i) a[i] = As[k][tm + i];
#pragma unroll
            for (int j = 0; j < 4; ++j) b[j] = Bs[k][tn + j];
#pragma unroll
            for (int i = 0; i < 4; ++i)
#pragma unroll
                for (int j = 0; j < 4; ++j)
                    acc[i][j] += a[i] * b[j];
        }
        __syncthreads();
    }

#pragma unroll
    for (int i = 0; i < 4; ++i) {
        int gm = m0 + tm + i;
        if (gm >= M2) continue;
        int src = (gm >= M1) ? 1 : 0;
        int row = gm - src * M1;
        int bb  = row / NN;
        int nn  = row % NN;
#pragma unroll
        for (int j = 0; j < 4; ++j) {
            int gn = n0 + tn + j;
            float val = acc[i][j] + bias[gn];
            int part = gn / DD;
            int dcol = gn % DD;
            int h = dcol / HD;
            int d = dcol % HD;
            uint16_t* dst;
            if (src == 0) dst = (part == 0) ? qA : (part == 1) ? kA : vA;
            else { if (part == 2) continue; dst = (part == 0) ? qF : kF; }
            dst[(((size_t)bb * HH + h) * NN + nn) * HD + d] = f2bf(val);
        }
    }
}

// ---------------------------------------------------------------------------
// K2: softmax-1 denominators.  Ssum[b][c][n] = sum_m exp(scale * q_c[n].k_c[m])
//     (logits are tiny: no max subtraction needed).  One WG per (b, c, 32 rows).
// ---------------------------------------------------------------------------
__global__ __launch_bounds__(256) void k_sum1(
    const uint16_t* __restrict__ qA, const uint16_t* __restrict__ kA,
    const uint16_t* __restrict__ qF, const uint16_t* __restrict__ kF,
    float* __restrict__ Ssum)
{
    __shared__ uint32_t qs[32 * 25];
    __shared__ uint32_t ks[64 * 25];
    __shared__ float red[8][33];
    const float scale = 0.14433756729740643f; // 48^-0.5
    const int t  = threadIdx.x;
    const int n0 = blockIdx.x * 32;
    const int c  = blockIdx.y;
    const int b  = blockIdx.z;
    const int h  = c & 15;
    const uint32_t* q32 = (const uint32_t*)((c < 16) ? qA : qF) + ((size_t)(b * HH + h) * NN) * 24;
    const uint32_t* k32 = (const uint32_t*)((c < 16) ? kA : kF) + ((size_t)(b * HH + h) * NN) * 24;

    for (int i = t; i < 32 * 24; i += 256) {
        int r = i / 24, dd = i % 24;
        int n = n0 + r;
        qs[r * 25 + dd] = (n < NN) ? q32[(size_t)n * 24 + dd] : 0u;
    }
    __syncthreads();

    const int r = t & 31, g = t >> 5;
    float sum = 0.f;
    for (int m0 = 0; m0 < NN; m0 += 64) {
        __syncthreads();
        for (int i = t; i < 64 * 24; i += 256) {
            int mm = i / 24, dd = i % 24;
            int m = m0 + mm;
            ks[mm * 25 + dd] = (m < NN) ? k32[(size_t)m * 24 + dd] : 0u;
        }
        __syncthreads();
#pragma unroll
        for (int ii = 0; ii < 8; ++ii) {
            int mm = g * 8 + ii;
            int m = m0 + mm;
            if (m < NN) {
                float s = dot48(&qs[r * 25], &ks[mm * 25]);
                sum += __expf(s * scale);
            }
        }
    }
    red[g][r] = sum;
    __syncthreads();
    if (t < 32) {
        float tot = 0.f;
#pragma unroll
        for (int gg = 0; gg < 8; ++gg) tot += red[gg][t];
        int n = n0 + t;
        if (n < NN) Ssum[((size_t)b * CC + c) * NN + n] = tot;
    }
}

// ---------------------------------------------------------------------------
// K3: fused  recompute-scores -> p=exp(s)/S -> conv mix -> e=exp(mixed+cb)
//           -> single-pass softmax-2 + PV (unnormalized accumulate, divide at end)
//     WG = (b, 16 q-rows); 256 threads = 16 rows x 16 (m or o) lanes.
// ---------------------------------------------------------------------------
__global__ __launch_bounds__(256) void k_mix_pv(
    const uint16_t* __restrict__ qA, const uint16_t* __restrict__ kA, const uint16_t* __restrict__ vA,
    const uint16_t* __restrict__ qF, const uint16_t* __restrict__ kF,
    const float* __restrict__ Ssum, const float* __restrict__ conv_w, const float* __restrict__ conv_b,
    float* __restrict__ weighted)
{
    __shared__ uint32_t qall[32 * 16 * 25];  // 50 KB  q for all 32 channels, 16 rows
    __shared__ uint32_t kt[32 * 16 * 25];    // 50 KB  k tile, all channels, 16 m
    __shared__ uint32_t vt[16 * 16 * 25];    // 25 KB  v tile
    __shared__ float e_lds[16 * 16 * 17];    // 17 KB  e[r][m][o], o-stride 17 (bank pad)
    __shared__ float invS[32 * 16];
    __shared__ float cw[16 * 32];
    __shared__ float cb[16];
    const float scale = 0.14433756729740643f;
    const int t  = threadIdx.x;
    const int n0 = blockIdx.x * 16;
    const int b  = blockIdx.y;

    for (int i = t; i < 512; i += 256) cw[i] = conv_w[i];
    if (t < 16) cb[t] = conv_b[t];
    for (int i = t; i < 512; i += 256) {
        int c = i >> 4, r = i & 15;
        int n = n0 + r;
        invS[i] = (n < NN) ? 1.0f / Ssum[((size_t)b * CC + c) * NN + n] : 0.f;
    }
    for (int i = t; i < 32 * 16 * 24; i += 256) {
        int c = i / 384, rem = i % 384;
        int r = rem / 24, dd = rem % 24;
        int hh = c & 15;
        const uint32_t* q32 = (const uint32_t*)((c < 16) ? qA : qF) + ((size_t)(b * HH + hh) * NN) * 24;
        int n = n0 + r;
        qall[(c * 16 + r) * 25 + dd] = (n < NN) ? q32[(size_t)n * 24 + dd] : 0u;
    }

    const int rr   = t >> 4;   // row 0..15
    const int mloc = t & 15;   // m within tile (score phase)
    const int u    = t & 15;   // output head (pv phase)
    float acc[48] = {};
    float denom = 0.f;
    __syncthreads();

    for (int m0 = 0; m0 < NN; m0 += 16) {
        // stage k (all 32 channels) and v tiles
        for (int i = t; i < 32 * 16 * 24; i += 256) {
            int c = i / 384, rem = i % 384;
            int mm = rem / 24, dd = rem % 24;
            int hh = c & 15;
            const uint32_t* k32 = (const uint32_t*)((c < 16) ? kA : kF) + ((size_t)(b * HH + hh) * NN) * 24;
            int m = m0 + mm;
            kt[(c * 16 + mm) * 25 + dd] = (m < NN) ? k32[(size_t)m * 24 + dd] : 0u;
        }
        for (int i = t; i < 16 * 16 * 24; i += 256) {
            int o = i / 384, rem = i % 384;
            int mm = rem / 24, dd = rem % 24;
            const uint32_t* v32 = (const uint32_t*)vA + ((size_t)(b * HH + o) * NN) * 24;
            int m = m0 + mm;
            vt[(o * 16 + mm) * 25 + dd] = (m < NN) ? v32[(size_t)m * 24 + dd] : 0u;
        }
        __syncthreads();

        // score + mix phase: thread (rr, mloc)
        float mixed[16];
#pragma unroll
        for (int o = 0; o < 16; ++o) mixed[o] = 0.f;
        for (int c = 0; c < 32; ++c) {
            float s = dot48(&qall[(c * 16 + rr) * 25], &kt[(c * 16 + mloc) * 25]);
            float p = __expf(s * scale) * invS[c * 16 + rr];
#pragma unroll
            for (int o = 0; o < 16; ++o) mixed[o] += cw[o * 32 + c] * p;
        }
        {
            int m = m0 + mloc;
#pragma unroll
            for (int o = 0; o < 16; ++o) {
                float e = (m < NN) ? __expf(mixed[o] + cb[o]) : 0.f;
                e_lds[(rr * 16 + mloc) * 17 + o] = e;
            }
        }
        __syncthreads();

        // PV phase: thread (rr, u)
#pragma unroll
        for (int mm = 0; mm < 16; ++mm) {
            float ev = e_lds[(rr * 16 + mm) * 17 + u];
            denom += ev;
            const uint32_t* vp = &vt[(u * 16 + mm) * 25];
#pragma unroll
            for (int dd = 0; dd < 24; ++dd) {
                uint32_t vu = vp[dd];
                acc[dd * 2]     += ev * bf_lo(vu);
                acc[dd * 2 + 1] += ev * bf_hi(vu);
            }
        }
        __syncthreads();
    }

    int n = n0 + rr;
    if (n < NN) {
        float inv = 1.0f / denom;
        float* wp = weighted + ((size_t)b * NN + n) * DD + u * HD;
#pragma unroll
        for (int d = 0; d < HD; ++d) wp[d] = acc[d] * inv;
    }
}

// ---------------------------------------------------------------------------
// K4: out = weighted @ proj_w^T + proj_b.  M=4616, N=768, K=768, f32.
// ---------------------------------------------------------------------------
__global__ __launch_bounds__(256) void k_proj(
    const float* __restrict__ A, const float* __restrict__ w, const float* __restrict__ bias,
    float* __restrict__ out)
{
    __shared__ float As[16][65];
    __shared__ float Bs[16][65];
    const int t    = threadIdx.x;
    const int m0   = blockIdx.x * 64;
    const int n0   = blockIdx.y * 64;
    const int lrow = t >> 2;
    const int lk4  = (t & 3) << 2;
    const int tm   = (t & 15) << 2;
    const int tn   = (t >> 4) << 2;
    float acc[4][4] = {};

    for (int k0 = 0; k0 < DD; k0 += 16) {
        int gm = m0 + lrow;
        float4 av = make_float4(0.f, 0.f, 0.f, 0.f);
        if (gm < M1) av = *reinterpret_cast<const float4*>(A + (size_t)gm * DD + k0 + lk4);
        As[lk4 + 0][lrow] = av.x; As[lk4 + 1][lrow] = av.y;
        As[lk4 + 2][lrow] = av.z; As[lk4 + 3][lrow] = av.w;
        int gj = n0 + lrow;
        float4 bv = *reinterpret_cast<const float4*>(w + (size_t)gj * DD + k0 + lk4);
        Bs[lk4 + 0][lrow] = bv.x; Bs[lk4 + 1][lrow] = bv.y;
        Bs[lk4 + 2][lrow] = bv.z; Bs[lk4 + 3][lrow] = bv.w;
        __syncthreads();
#pragma unroll
        for (int k = 0; k < 16; ++k) {
            float a[4], b[4];
#pragma unroll
            for (int i = 0; i < 4; ++i) a[i] = As[k][tm + i];
#pragma unroll
            for (int j = 0; j < 4; ++j) b[j] = Bs[k][tn + j];
#pragma unroll
            for (int i = 0; i < 4; ++i)
#pragma unroll
                for (int j = 0; j < 4; ++j)
                    acc[i][j] += a[i] * b[j];
        }
        __syncthreads();
    }

#pragma unroll
    for (int i = 0; i < 4; ++i) {
        int gm = m0 + tm + i;
        if (gm >= M1) continue;
#pragma unroll
        for (int j = 0; j < 4; ++j) {
            int gn = n0 + tn + j;
            out[(size_t)gm * DD + gn] = acc[i][j] + bias[gn];
        }
    }
}

extern "C" void kernel_launch(void* const* d_in, const int* in_sizes, int n_in,
                              void* d_out, int out_size, void* d_ws, size_t ws_size,
                              hipStream_t stream) {
    const float* x      = (const float*)d_in[0];
    const float* xf     = (const float*)d_in[1];
    const float* qkv_w  = (const float*)d_in[2];
    const float* qkv_b  = (const float*)d_in[3];
    const float* conv_w = (const float*)d_in[4];
    const float* conv_b = (const float*)d_in[5];
    const float* proj_w = (const float*)d_in[6];
    const float* proj_b = (const float*)d_in[7];
    float* out = (float*)d_out;

    const size_t SZ = (size_t)BB * HH * NN * HD;   // 3,545,088 elems
    uint16_t* qA = (uint16_t*)d_ws;
    uint16_t* kA = qA + SZ;
    uint16_t* vA = kA + SZ;
    uint16_t* qF = vA + SZ;
    uint16_t* kF = qF + SZ;
    float* Ssum     = (float*)(kF + SZ);
    float* weighted = Ssum + (size_t)BB * CC * NN;
    // total workspace use: 5*SZ*2 + (B*C*N + B*N*D)*4  ~= 50.2 MB

    k_qkv  <<<dim3(145, 36, 1), 256, 0, stream>>>(x, xf, qkv_w, qkv_b, qA, kA, vA, qF, kF);
    k_sum1 <<<dim3(19, 32, 8),  256, 0, stream>>>(qA, kA, qF, kF, Ssum);
    k_mix_pv<<<dim3(37, 8, 1),  256, 0, stream>>>(qA, kA, vA, qF, kF, Ssum, conv_w, conv_b, weighted);
    k_proj <<<dim3(73, 12, 1),  256, 0, stream>>>(weighted, proj_w, proj_b, out);
}

// Round 3
// 3224.183 us; speedup vs baseline: 1.5088x; 1.5088x over previous
//
#include <hip/hip_runtime.h>
#include <stdint.h>

#define BB 8
#define NN 577
#define DD 768
#define HH 16
#define HD 48
#define CC 32
#define M1 4616   /* B*N  */
#define M2 9232   /* 2*B*N */

static __device__ __forceinline__ float bf_lo(uint32_t u){ return __uint_as_float(u << 16); }
static __device__ __forceinline__ float bf_hi(uint32_t u){ return __uint_as_float(u & 0xffff0000u); }
static __device__ __forceinline__ uint16_t f2bf(float f){
    uint32_t u = __float_as_uint(f);
    return (uint16_t)((u + 0x7fffu + ((u >> 16) & 1u)) >> 16);
}

// 48-term bf16x2 dot product with 4 independent accumulation chains
static __device__ __forceinline__ float dot48(const uint32_t* qp, const uint32_t* kp) {
    float s0 = 0.f, s1 = 0.f, s2 = 0.f, s3 = 0.f;
#pragma unroll
    for (int dd = 0; dd < 24; dd += 2) {
        uint32_t q0 = qp[dd],     k0 = kp[dd];
        uint32_t q1 = qp[dd + 1], k1 = kp[dd + 1];
        s0 += bf_lo(q0) * bf_lo(k0);
        s1 += bf_hi(q0) * bf_hi(k0);
        s2 += bf_lo(q1) * bf_lo(k1);
        s3 += bf_hi(q1) * bf_hi(k1);
    }
    return (s0 + s1) + (s2 + s3);
}

// ---------------------------------------------------------------------------
// K1: qkv = [x; x_freq] @ qkv_w^T + qkv_b, scattered to bf16 head-layout.
// ---------------------------------------------------------------------------
__global__ __launch_bounds__(256) void k_qkv(
    const float* __restrict__ x, const float* __restrict__ xf,
    const float* __restrict__ w, const float* __restrict__ bias,
    uint16_t* __restrict__ qA, uint16_t* __restrict__ kA, uint16_t* __restrict__ vA,
    uint16_t* __restrict__ qF, uint16_t* __restrict__ kF)
{
    __shared__ float As[16][65];
    __shared__ float Bs[16][65];
    const int t    = threadIdx.x;
    const int m0   = blockIdx.x * 64;
    const int n0   = blockIdx.y * 64;
    const int lrow = t >> 2;
    const int lk4  = (t & 3) << 2;
    const int tm   = (t & 15) << 2;
    const int tn   = (t >> 4) << 2;
    float acc[4][4] = {};

    for (int k0 = 0; k0 < DD; k0 += 16) {
        int gm = m0 + lrow;
        float4 av = make_float4(0.f, 0.f, 0.f, 0.f);
        if (gm < M2) {
            const float* src = (gm < M1) ? (x + (size_t)gm * DD) : (xf + (size_t)(gm - M1) * DD);
            av = *reinterpret_cast<const float4*>(src + k0 + lk4);
        }
        As[lk4 + 0][lrow] = av.x; As[lk4 + 1][lrow] = av.y;
        As[lk4 + 2][lrow] = av.z; As[lk4 + 3][lrow] = av.w;
        int gj = n0 + lrow;
        float4 bv = *reinterpret_cast<const float4*>(w + (size_t)gj * DD + k0 + lk4);
        Bs[lk4 + 0][lrow] = bv.x; Bs[lk4 + 1][lrow] = bv.y;
        Bs[lk4 + 2][lrow] = bv.z; Bs[lk4 + 3][lrow] = bv.w;
        __syncthreads();
#pragma unroll
        for (int k = 0; k < 16; ++k) {
            float a[4], b[4];
#pragma unroll
            for (int i = 0; i < 4; ++i) a[i] = As[k][tm + i];
#pragma unroll
            for (int j = 0; j < 4; ++j) b[j] = Bs[k][tn + j];
#pragma unroll
            for (int i = 0; i < 4; ++i)
#pragma unroll
                for (int j = 0; j < 4; ++j)
                    acc[i][j] += a[i] * b[j];
        }
        __syncthreads();
    }

#pragma unroll
    for (int i = 0; i < 4; ++i) {
        int gm = m0 + tm + i;
        if (gm >= M2) continue;
        int src = (gm >= M1) ? 1 : 0;
        int row = gm - src * M1;
        int bb  = row / NN;
        int nn  = row % NN;
#pragma unroll
        for (int j = 0; j < 4; ++j) {
            int gn = n0 + tn + j;
            float val = acc[i][j] + bias[gn];
            int part = gn / DD;
            int dcol = gn % DD;
            int h = dcol / HD;
            int d = dcol % HD;
            uint16_t* dst;
            if (src == 0) dst = (part == 0) ? qA : (part == 1) ? kA : vA;
            else { if (part == 2) continue; dst = (part == 0) ? qF : kF; }
            dst[(((size_t)bb * HH + h) * NN + nn) * HD + d] = f2bf(val);
        }
    }
}

// ---------------------------------------------------------------------------
// K2: softmax-1 denominators (logits tiny: no max subtraction needed).
// ---------------------------------------------------------------------------
__global__ __launch_bounds__(256) void k_sum1(
    const uint16_t* __restrict__ qA, const uint16_t* __restrict__ kA,
    const uint16_t* __restrict__ qF, const uint16_t* __restrict__ kF,
    float* __restrict__ Ssum)
{
    __shared__ uint32_t qs[32 * 25];
    __shared__ uint32_t ks[64 * 25];
    __shared__ float red[8][33];
    const float scale = 0.14433756729740643f; // 48^-0.5
    const int t  = threadIdx.x;
    const int n0 = blockIdx.x * 32;
    const int c  = blockIdx.y;
    const int b  = blockIdx.z;
    const int h  = c & 15;
    const uint32_t* q32 = (const uint32_t*)((c < 16) ? qA : qF) + ((size_t)(b * HH + h) * NN) * 24;
    const uint32_t* k32 = (const uint32_t*)((c < 16) ? kA : kF) + ((size_t)(b * HH + h) * NN) * 24;

    for (int i = t; i < 32 * 24; i += 256) {
        int r = i / 24, dd = i % 24;
        int n = n0 + r;
        qs[r * 25 + dd] = (n < NN) ? q32[(size_t)n * 24 + dd] : 0u;
    }
    __syncthreads();

    const int r = t & 31, g = t >> 5;
    float sum = 0.f;
    for (int m0 = 0; m0 < NN; m0 += 64) {
        __syncthreads();
        for (int i = t; i < 64 * 24; i += 256) {
            int mm = i / 24, dd = i % 24;
            int m = m0 + mm;
            ks[mm * 25 + dd] = (m < NN) ? k32[(size_t)m * 24 + dd] : 0u;
        }
        __syncthreads();
#pragma unroll
        for (int ii = 0; ii < 8; ++ii) {
            int mm = g * 8 + ii;
            int m = m0 + mm;
            if (m < NN) {
                float s = dot48(&qs[r * 25], &ks[mm * 25]);
                sum += __expf(s * scale);
            }
        }
    }
    red[g][r] = sum;
    __syncthreads();
    if (t < 32) {
        float tot = 0.f;
#pragma unroll
        for (int gg = 0; gg < 8; ++gg) tot += red[gg][t];
        int n = n0 + t;
        if (n < NN) Ssum[((size_t)b * CC + c) * NN + n] = tot;
    }
}

// ---------------------------------------------------------------------------
// K3 v2: fused scores -> softmax1 -> conv mix -> exp -> PV (single pass).
//   - Q/K staged in LDS as f32 (unpack once), c-chunks of 4 (LDS 75.3KB -> 2 blk/CU)
//   - m-dimension split over gridDim.z slices; per-slice partials + k_red
//   - threads: 256 = 16 rows x 16 (m | head)
// ---------------------------------------------------------------------------
__global__ __launch_bounds__(256, 2) void k_mix_pv(
    const uint16_t* __restrict__ qA, const uint16_t* __restrict__ kA, const uint16_t* __restrict__ vA,
    const uint16_t* __restrict__ qF, const uint16_t* __restrict__ kF,
    const float* __restrict__ Ssum, const float* __restrict__ conv_w, const float* __restrict__ conv_b,
    float* __restrict__ weighted, float* __restrict__ pnum, float* __restrict__ pden, int NS)
{
    __shared__ __align__(16) float4   qch4[4 * 16 * 13];   // 13,312 B  (4c x 16r x 48 f32, row stride 13 f4)
    __shared__ __align__(16) float4   kch4[4 * 16 * 13];   // 13,312 B
    __shared__ __align__(16) uint4    vt4[16 * 113];       // 28,928 B  (16o x 16m x 24 u32 bf16, o-stride 113 u4, m-stride 7 u4)
    __shared__ __align__(16) float    e_lds[16 * 16 * 17]; // 17,408 B
    __shared__ __align__(16) float    invS_l[32 * 16];     //  2,048 B
    __shared__ __align__(16) float    cwT[32 * 16];        //  2,048 B  cwT[c][o]
    __shared__ float                  cb_l[16];
    const float scale = 0.14433756729740643f;
    const int t     = threadIdx.x;
    const int n0    = blockIdx.x * 16;
    const int b     = blockIdx.y;
    const int slice = blockIdx.z;

    const uint32_t* q32A = (const uint32_t*)qA + (size_t)b * HH * NN * 24;
    const uint32_t* q32F = (const uint32_t*)qF + (size_t)b * HH * NN * 24;
    const uint32_t* k32A = (const uint32_t*)kA + (size_t)b * HH * NN * 24;
    const uint32_t* k32F = (const uint32_t*)kF + (size_t)b * HH * NN * 24;
    const uint32_t* v32  = (const uint32_t*)vA + (size_t)b * HH * NN * 24;

    // one-time staging: invS, cwT (transposed), cb
    for (int i = t; i < 512; i += 256) {
        int c = i >> 4, r = i & 15;
        int n = n0 + r;
        invS_l[i] = (n < NN) ? 1.0f / Ssum[((size_t)b * CC + c) * NN + n] : 0.f;
        int o2 = i >> 5, c2 = i & 31;
        cwT[c2 * 16 + o2] = conv_w[o2 * 32 + c2];
    }
    if (t < 16) cb_l[t] = conv_b[t];

    const int rr = t >> 4;    // q-row 0..15
    const int u  = t & 15;    // m-lane (score) / head (PV)
    float acc[48] = {};
    float denom = 0.f;

    // staging identities (division-free)
    const int srow = t >> 2;        // 0..63 : (cc, r) row for q/k chunk staging
    const int sq   = t & 3;         // quarter of a 48-f32 row
    const int scc  = srow >> 4;     // 0..3
    const int sr   = srow & 15;
    const int vo   = t >> 4;        // v-stage: head
    const int vm   = t & 15;        // v-stage: m within tile

    for (int mt = slice; mt < 37; mt += NS) {
        const int m0 = mt * 16;

        // ---- stage V tile (bf16 u32-packed), one row per thread ----
        {
            int m = m0 + vm;
            uint4 z4 = make_uint4(0u, 0u, 0u, 0u);
            if (m < NN) {
                const uint4* g = (const uint4*)(v32 + ((size_t)vo * NN + m) * 24);
#pragma unroll
                for (int i = 0; i < 6; ++i) vt4[vo * 113 + vm * 7 + i] = g[i];
            } else {
#pragma unroll
                for (int i = 0; i < 6; ++i) vt4[vo * 113 + vm * 7 + i] = z4;
            }
        }

        float mixed[16];
#pragma unroll
        for (int o = 0; o < 16; ++o) mixed[o] = 0.f;

        // ---- c-chunks of 4: stage q/k as f32, then score+mix ----
        for (int c0 = 0; c0 < 32; c0 += 4) {
            // stage q chunk: thread -> (scc, sr, quarter sq)
            {
                int c = c0 + scc;
                int h = c & 15;
                const uint32_t* src = (c < 16) ? q32A : q32F;
                int n = n0 + sr;
                float4 f0 = make_float4(0.f,0.f,0.f,0.f), f1 = f0, f2 = f0;
                if (n < NN) {
                    const uint2* g = (const uint2*)(src + ((size_t)h * NN + n) * 24 + sq * 6);
                    uint2 w0 = g[0], w1 = g[1], w2 = g[2];
                    f0 = make_float4(bf_lo(w0.x), bf_hi(w0.x), bf_lo(w0.y), bf_hi(w0.y));
                    f1 = make_float4(bf_lo(w1.x), bf_hi(w1.x), bf_lo(w1.y), bf_hi(w1.y));
                    f2 = make_float4(bf_lo(w2.x), bf_hi(w2.x), bf_lo(w2.y), bf_hi(w2.y));
                }
                float4* dst = &qch4[(scc * 16 + sr) * 13 + sq * 3];
                dst[0] = f0; dst[1] = f1; dst[2] = f2;
            }
            // stage k chunk
            {
                int c = c0 + scc;
                int h = c & 15;
                const uint32_t* src = (c < 16) ? k32A : k32F;
                int m = m0 + sr;
                float4 f0 = make_float4(0.f,0.f,0.f,0.f), f1 = f0, f2 = f0;
                if (m < NN) {
                    const uint2* g = (const uint2*)(src + ((size_t)h * NN + m) * 24 + sq * 6);
                    uint2 w0 = g[0], w1 = g[1], w2 = g[2];
                    f0 = make_float4(bf_lo(w0.x), bf_hi(w0.x), bf_lo(w0.y), bf_hi(w0.y));
                    f1 = make_float4(bf_lo(w1.x), bf_hi(w1.x), bf_lo(w1.y), bf_hi(w1.y));
                    f2 = make_float4(bf_lo(w2.x), bf_hi(w2.x), bf_lo(w2.y), bf_hi(w2.y));
                }
                float4* dst = &kch4[(scc * 16 + sr) * 13 + sq * 3];
                dst[0] = f0; dst[1] = f1; dst[2] = f2;
            }
            __syncthreads();

            // score + mix for 4 channels; thread = (rr, mloc=u)
#pragma unroll
            for (int cc = 0; cc < 4; ++cc) {
                const float4* qp = &qch4[(cc * 16 + rr) * 13];
                const float4* kp = &kch4[(cc * 16 + u) * 13];
                float s0 = 0.f, s1 = 0.f, s2 = 0.f, s3 = 0.f;
#pragma unroll
                for (int i = 0; i < 12; ++i) {
                    float4 a = qp[i], bb4 = kp[i];
                    s0 += a.x * bb4.x; s1 += a.y * bb4.y;
                    s2 += a.z * bb4.z; s3 += a.w * bb4.w;
                }
                float s = (s0 + s1) + (s2 + s3);
                int c = c0 + cc;
                float p = __expf(s * scale) * invS_l[c * 16 + rr];
                const float4* cwp = (const float4*)&cwT[c * 16];
#pragma unroll
                for (int j = 0; j < 4; ++j) {
                    float4 w4 = cwp[j];
                    mixed[4 * j + 0] += w4.x * p;
                    mixed[4 * j + 1] += w4.y * p;
                    mixed[4 * j + 2] += w4.z * p;
                    mixed[4 * j + 3] += w4.w * p;
                }
            }
            __syncthreads();
        }

        // ---- e = exp(mixed + cb)  (zero for m >= NN: denominator correctness) ----
        {
            int m = m0 + u;
            float* ep = &e_lds[(rr * 16 + u) * 17];
            if (m < NN) {
#pragma unroll
                for (int o = 0; o < 16; ++o) ep[o] = __expf(mixed[o] + cb_l[o]);
            } else {
#pragma unroll
                for (int o = 0; o < 16; ++o) ep[o] = 0.f;
            }
        }
        __syncthreads();

        // ---- PV: thread (rr, head u) ----
#pragma unroll
        for (int mm = 0; mm < 16; ++mm) {
            float ev = e_lds[(rr * 16 + mm) * 17 + u];
            denom += ev;
            const uint4* vp = &vt4[u * 113 + mm * 7];
#pragma unroll
            for (int i = 0; i < 6; ++i) {
                uint4 vv = vp[i];
                acc[i * 8 + 0] += ev * bf_lo(vv.x); acc[i * 8 + 1] += ev * bf_hi(vv.x);
                acc[i * 8 + 2] += ev * bf_lo(vv.y); acc[i * 8 + 3] += ev * bf_hi(vv.y);
                acc[i * 8 + 4] += ev * bf_lo(vv.z); acc[i * 8 + 5] += ev * bf_hi(vv.z);
                acc[i * 8 + 6] += ev * bf_lo(vv.w); acc[i * 8 + 7] += ev * bf_hi(vv.w);
            }
        }
        __syncthreads();
    }

    // ---- write out ----
    int n = n0 + rr;
    if (n < NN) {
        if (NS == 1) {
            float inv = 1.0f / denom;
            float4* wp = (float4*)(weighted + ((size_t)b * NN + n) * DD + u * HD);
#pragma unroll
            for (int i = 0; i < 12; ++i)
                wp[i] = make_float4(acc[4*i]*inv, acc[4*i+1]*inv, acc[4*i+2]*inv, acc[4*i+3]*inv);
        } else {
            float4* np = (float4*)(pnum + (((size_t)slice * BB + b) * NN + n) * DD + u * HD);
#pragma unroll
            for (int i = 0; i < 12; ++i)
                np[i] = make_float4(acc[4*i], acc[4*i+1], acc[4*i+2], acc[4*i+3]);
            pden[(((size_t)slice * BB + b) * NN + n) * 16 + u] = denom;
        }
    }
}

// ---------------------------------------------------------------------------
// K3b: reduce slices + divide.  grid (3, B*N), 256 thr.
// ---------------------------------------------------------------------------
__global__ __launch_bounds__(256) void k_red(
    const float* __restrict__ pnum, const float* __restrict__ pden,
    float* __restrict__ weighted, int NS)
{
    int col = blockIdx.x * 256 + threadIdx.x;   // 0..767
    int bn  = blockIdx.y;                       // 0..4615
    int o   = (col * 1366) >> 16;               // col / 48
    float sn = 0.f, sd = 0.f;
    for (int s = 0; s < NS; ++s) {
        sn += pnum[((size_t)s * M1 + bn) * DD + col];
        sd += pden[((size_t)s * M1 + bn) * 16 + o];
    }
    weighted[(size_t)bn * DD + col] = sn / sd;
}

// ---------------------------------------------------------------------------
// K4: out = weighted @ proj_w^T + proj_b.
// ---------------------------------------------------------------------------
__global__ __launch_bounds__(256) void k_proj(
    const float* __restrict__ A, const float* __restrict__ w, const float* __restrict__ bias,
    float* __restrict__ out)
{
    __shared__ float As[16][65];
    __shared__ float Bs[16][65];
    const int t    = threadIdx.x;
    const int m0   = blockIdx.x * 64;
    const int n0   = blockIdx.y * 64;
    const int lrow = t >> 2;
    const int lk4  = (t & 3) << 2;
    const int tm   = (t & 15) << 2;
    const int tn   = (t >> 4) << 2;
    float acc[4][4] = {};

    for (int k0 = 0; k0 < DD; k0 += 16) {
        int gm = m0 + lrow;
        float4 av = make_float4(0.f, 0.f, 0.f, 0.f);
        if (gm < M1) av = *reinterpret_cast<const float4*>(A + (size_t)gm * DD + k0 + lk4);
        As[lk4 + 0][lrow] = av.x; As[lk4 + 1][lrow] = av.y;
        As[lk4 + 2][lrow] = av.z; As[lk4 + 3][lrow] = av.w;
        int gj = n0 + lrow;
        float4 bv = *reinterpret_cast<const float4*>(w + (size_t)gj * DD + k0 + lk4);
        Bs[lk4 + 0][lrow] = bv.x; Bs[lk4 + 1][lrow] = bv.y;
        Bs[lk4 + 2][lrow] = bv.z; Bs[lk4 + 3][lrow] = bv.w;
        __syncthreads();
#pragma unroll
        for (int k = 0; k < 16; ++k) {
            float a[4], b[4];
#pragma unroll
            for (int i = 0; i < 4; ++i) a[i] = As[k][tm + i];
#pragma unroll
            for (int j = 0; j < 4; ++j) b[j] = Bs[k][tn + j];
#pragma unroll
            for (int i = 0; i < 4; ++i)
#pragma unroll
                for (int j = 0; j < 4; ++j)
                    acc[i][j] += a[i] * b[j];
        }
        __syncthreads();
    }

#pragma unroll
    for (int i = 0; i < 4; ++i) {
        int gm = m0 + tm + i;
        if (gm >= M1) continue;
#pragma unroll
        for (int j = 0; j < 4; ++j) {
            int gn = n0 + tn + j;
            out[(size_t)gm * DD + gn] = acc[i][j] + bias[gn];
        }
    }
}

extern "C" void kernel_launch(void* const* d_in, const int* in_sizes, int n_in,
                              void* d_out, int out_size, void* d_ws, size_t ws_size,
                              hipStream_t stream) {
    const float* x      = (const float*)d_in[0];
    const float* xf     = (const float*)d_in[1];
    const float* qkv_w  = (const float*)d_in[2];
    const float* qkv_b  = (const float*)d_in[3];
    const float* conv_w = (const float*)d_in[4];
    const float* conv_b = (const float*)d_in[5];
    const float* proj_w = (const float*)d_in[6];
    const float* proj_b = (const float*)d_in[7];
    float* out = (float*)d_out;

    const size_t SZ = (size_t)BB * HH * NN * HD;   // 3,545,088 elems
    uint16_t* qA = (uint16_t*)d_ws;
    uint16_t* kA = qA + SZ;
    uint16_t* vA = kA + SZ;
    uint16_t* qF = vA + SZ;
    uint16_t* kF = qF + SZ;
    float* Ssum     = (float*)(kF + SZ);
    float* weighted = Ssum + (size_t)BB * CC * NN;
    float* pnum     = weighted + (size_t)M1 * DD;
    // per-slice partial: num (M1*768 f32) + den (M1*16 f32)
    const size_t base_bytes  = (size_t)(5 * SZ) * 2 + ((size_t)BB * CC * NN + (size_t)M1 * DD) * 4;
    const size_t slice_bytes = ((size_t)M1 * DD + (size_t)M1 * 16) * 4;
    int NS = 1;
    if (ws_size >= base_bytes + 4 * slice_bytes)      NS = 4;
    else if (ws_size >= base_bytes + 2 * slice_bytes) NS = 2;
    float* pden = pnum + (size_t)NS * M1 * DD;

    k_qkv  <<<dim3(145, 36, 1), 256, 0, stream>>>(x, xf, qkv_w, qkv_b, qA, kA, vA, qF, kF);
    k_sum1 <<<dim3(19, 32, 8),  256, 0, stream>>>(qA, kA, qF, kF, Ssum);
    k_mix_pv<<<dim3(37, 8, NS), 256, 0, stream>>>(qA, kA, vA, qF, kF, Ssum, conv_w, conv_b,
                                                  weighted, pnum, pden, NS);
    if (NS > 1)
        k_red<<<dim3(3, M1), 256, 0, stream>>>(pnum, pden, weighted, NS);
    k_proj <<<dim3(73, 12, 1),  256, 0, stream>>>(weighted, proj_w, proj_b, out);
}

// Round 4
// 2440.981 us; speedup vs baseline: 1.9929x; 1.3209x over previous
//
#include <hip/hip_runtime.h>
#include <stdint.h>

#define BB 8
#define NN 577
#define DD 768
#define HH 16
#define HD 48
#define CC 32
#define M1 4616   /* B*N  */
#define M2 9232   /* 2*B*N */

static __device__ __forceinline__ float bf_lo(uint32_t u){ return __uint_as_float(u << 16); }
static __device__ __forceinline__ float bf_hi(uint32_t u){ return __uint_as_float(u & 0xffff0000u); }
static __device__ __forceinline__ uint16_t f2bf(float f){
    uint32_t u = __float_as_uint(f);
    return (uint16_t)((u + 0x7fffu + ((u >> 16) & 1u)) >> 16);
}

// 48-term bf16x2 dot product with 4 independent accumulation chains
static __device__ __forceinline__ float dot48(const uint32_t* qp, const uint32_t* kp) {
    float s0 = 0.f, s1 = 0.f, s2 = 0.f, s3 = 0.f;
#pragma unroll
    for (int dd = 0; dd < 24; dd += 2) {
        uint32_t q0 = qp[dd],     k0 = kp[dd];
        uint32_t q1 = qp[dd + 1], k1 = kp[dd + 1];
        s0 += bf_lo(q0) * bf_lo(k0);
        s1 += bf_hi(q0) * bf_hi(k0);
        s2 += bf_lo(q1) * bf_lo(k1);
        s3 += bf_hi(q1) * bf_hi(k1);
    }
    return (s0 + s1) + (s2 + s3);
}

// ---------------------------------------------------------------------------
// K1: qkv = [x; x_freq] @ qkv_w^T + qkv_b, scattered to bf16 head-layout.
// ---------------------------------------------------------------------------
__global__ __launch_bounds__(256) void k_qkv(
    const float* __restrict__ x, const float* __restrict__ xf,
    const float* __restrict__ w, const float* __restrict__ bias,
    uint16_t* __restrict__ qA, uint16_t* __restrict__ kA, uint16_t* __restrict__ vA,
    uint16_t* __restrict__ qF, uint16_t* __restrict__ kF)
{
    __shared__ float As[16][65];
    __shared__ float Bs[16][65];
    const int t    = threadIdx.x;
    const int m0   = blockIdx.x * 64;
    const int n0   = blockIdx.y * 64;
    const int lrow = t >> 2;
    const int lk4  = (t & 3) << 2;
    const int tm   = (t & 15) << 2;
    const int tn   = (t >> 4) << 2;
    float acc[4][4] = {};

    for (int k0 = 0; k0 < DD; k0 += 16) {
        int gm = m0 + lrow;
        float4 av = make_float4(0.f, 0.f, 0.f, 0.f);
        if (gm < M2) {
            const float* src = (gm < M1) ? (x + (size_t)gm * DD) : (xf + (size_t)(gm - M1) * DD);
            av = *reinterpret_cast<const float4*>(src + k0 + lk4);
        }
        As[lk4 + 0][lrow] = av.x; As[lk4 + 1][lrow] = av.y;
        As[lk4 + 2][lrow] = av.z; As[lk4 + 3][lrow] = av.w;
        int gj = n0 + lrow;
        float4 bv = *reinterpret_cast<const float4*>(w + (size_t)gj * DD + k0 + lk4);
        Bs[lk4 + 0][lrow] = bv.x; Bs[lk4 + 1][lrow] = bv.y;
        Bs[lk4 + 2][lrow] = bv.z; Bs[lk4 + 3][lrow] = bv.w;
        __syncthreads();
#pragma unroll
        for (int k = 0; k < 16; ++k) {
            float a[4], b[4];
#pragma unroll
            for (int i = 0; i < 4; ++i) a[i] = As[k][tm + i];
#pragma unroll
            for (int j = 0; j < 4; ++j) b[j] = Bs[k][tn + j];
#pragma unroll
            for (int i = 0; i < 4; ++i)
#pragma unroll
                for (int j = 0; j < 4; ++j)
                    acc[i][j] += a[i] * b[j];
        }
        __syncthreads();
    }

#pragma unroll
    for (int i = 0; i < 4; ++i) {
        int gm = m0 + tm + i;
        if (gm >= M2) continue;
        int src = (gm >= M1) ? 1 : 0;
        int row = gm - src * M1;
        int bb  = row / NN;
        int nn  = row % NN;
#pragma unroll
        for (int j = 0; j < 4; ++j) {
            int gn = n0 + tn + j;
            float val = acc[i][j] + bias[gn];
            int part = gn / DD;
            int dcol = gn % DD;
            int h = dcol / HD;
            int d = dcol % HD;
            uint16_t* dst;
            if (src == 0) dst = (part == 0) ? qA : (part == 1) ? kA : vA;
            else { if (part == 2) continue; dst = (part == 0) ? qF : kF; }
            dst[(((size_t)bb * HH + h) * NN + nn) * HD + d] = f2bf(val);
        }
    }
}

// ---------------------------------------------------------------------------
// K2: softmax-1 denominators (logits tiny: no max subtraction needed).
// ---------------------------------------------------------------------------
__global__ __launch_bounds__(256) void k_sum1(
    const uint16_t* __restrict__ qA, const uint16_t* __restrict__ kA,
    const uint16_t* __restrict__ qF, const uint16_t* __restrict__ kF,
    float* __restrict__ Ssum)
{
    __shared__ uint32_t qs[32 * 25];
    __shared__ uint32_t ks[64 * 25];
    __shared__ float red[8][33];
    const float scale = 0.14433756729740643f; // 48^-0.5
    const int t  = threadIdx.x;
    const int n0 = blockIdx.x * 32;
    const int c  = blockIdx.y;
    const int b  = blockIdx.z;
    const int h  = c & 15;
    const uint32_t* q32 = (const uint32_t*)((c < 16) ? qA : qF) + ((size_t)(b * HH + h) * NN) * 24;
    const uint32_t* k32 = (const uint32_t*)((c < 16) ? kA : kF) + ((size_t)(b * HH + h) * NN) * 24;

    for (int i = t; i < 32 * 24; i += 256) {
        int r = i / 24, dd = i % 24;
        int n = n0 + r;
        qs[r * 25 + dd] = (n < NN) ? q32[(size_t)n * 24 + dd] : 0u;
    }
    __syncthreads();

    const int r = t & 31, g = t >> 5;
    float sum = 0.f;
    for (int m0 = 0; m0 < NN; m0 += 64) {
        __syncthreads();
        for (int i = t; i < 64 * 24; i += 256) {
            int mm = i / 24, dd = i % 24;
            int m = m0 + mm;
            ks[mm * 25 + dd] = (m < NN) ? k32[(size_t)m * 24 + dd] : 0u;
        }
        __syncthreads();
#pragma unroll
        for (int ii = 0; ii < 8; ++ii) {
            int mm = g * 8 + ii;
            int m = m0 + mm;
            if (m < NN) {
                float s = dot48(&qs[r * 25], &ks[mm * 25]);
                sum += __expf(s * scale);
            }
        }
    }
    red[g][r] = sum;
    __syncthreads();
    if (t < 32) {
        float tot = 0.f;
#pragma unroll
        for (int gg = 0; gg < 8; ++gg) tot += red[gg][t];
        int n = n0 + t;
        if (n < NN) Ssum[((size_t)b * CC + c) * NN + n] = tot;
    }
}

// ---------------------------------------------------------------------------
// K3 v3: fused scores -> softmax1 -> conv mix -> exp -> PV (single pass).
//   - plain __launch_bounds__(256): NO vgpr cap (the ",2" in v2 forced 128
//     VGPRs and spilled acc[48]/mixed[16] -> 5.5 GB/dispatch scratch traffic)
//   - 1D grid, b = id & 7  => all blocks of a batch land on one XCD
//     (per-XCD working set ~4.4 MB ~= L2)
//   - LDS 77.3 KB => 2 blocks/CU as long as VGPR <= 256
// ---------------------------------------------------------------------------
__global__ __launch_bounds__(256) void k_mix_pv(
    const uint16_t* __restrict__ qA, const uint16_t* __restrict__ kA, const uint16_t* __restrict__ vA,
    const uint16_t* __restrict__ qF, const uint16_t* __restrict__ kF,
    const float* __restrict__ Ssum, const float* __restrict__ conv_w, const float* __restrict__ conv_b,
    float* __restrict__ weighted, float* __restrict__ pnum, float* __restrict__ pden, int NS)
{
    __shared__ __align__(16) float4   qch4[4 * 16 * 13];   // 13,312 B
    __shared__ __align__(16) float4   kch4[4 * 16 * 13];   // 13,312 B
    __shared__ __align__(16) uint4    vt4[16 * 113];       // 28,928 B
    __shared__ __align__(16) float    e_lds[16 * 16 * 17]; // 17,408 B
    __shared__ __align__(16) float    invS_l[32 * 16];     //  2,048 B
    __shared__ __align__(16) float    cwT[32 * 16];        //  2,048 B
    __shared__ float                  cb_l[16];
    const float scale = 0.14433756729740643f;
    const int t     = threadIdx.x;
    // 1D grid decode: id = b + 8*(slice + NS*ntile)  => xcd(b) pinning
    const int id    = blockIdx.x;
    const int b     = id & 7;
    const int rest  = id >> 3;
    const int slice = rest % NS;
    const int n0    = (rest / NS) * 16;

    const uint32_t* q32A = (const uint32_t*)qA + (size_t)b * HH * NN * 24;
    const uint32_t* q32F = (const uint32_t*)qF + (size_t)b * HH * NN * 24;
    const uint32_t* k32A = (const uint32_t*)kA + (size_t)b * HH * NN * 24;
    const uint32_t* k32F = (const uint32_t*)kF + (size_t)b * HH * NN * 24;
    const uint32_t* v32  = (const uint32_t*)vA + (size_t)b * HH * NN * 24;

    for (int i = t; i < 512; i += 256) {
        int c = i >> 4, r = i & 15;
        int n = n0 + r;
        invS_l[i] = (n < NN) ? 1.0f / Ssum[((size_t)b * CC + c) * NN + n] : 0.f;
        int o2 = i >> 5, c2 = i & 31;
        cwT[c2 * 16 + o2] = conv_w[o2 * 32 + c2];
    }
    if (t < 16) cb_l[t] = conv_b[t];

    const int rr = t >> 4;    // q-row 0..15
    const int u  = t & 15;    // m-lane (score) / head (PV)
    float acc[48] = {};
    float denom = 0.f;

    const int srow = t >> 2;
    const int sq   = t & 3;
    const int scc  = srow >> 4;
    const int sr   = srow & 15;
    const int vo   = t >> 4;
    const int vm   = t & 15;

    for (int mt = slice; mt < 37; mt += NS) {
        const int m0 = mt * 16;

        // ---- stage V tile ----
        {
            int m = m0 + vm;
            uint4 z4 = make_uint4(0u, 0u, 0u, 0u);
            if (m < NN) {
                const uint4* g = (const uint4*)(v32 + ((size_t)vo * NN + m) * 24);
#pragma unroll
                for (int i = 0; i < 6; ++i) vt4[vo * 113 + vm * 7 + i] = g[i];
            } else {
#pragma unroll
                for (int i = 0; i < 6; ++i) vt4[vo * 113 + vm * 7 + i] = z4;
            }
        }

        float mixed[16];
#pragma unroll
        for (int o = 0; o < 16; ++o) mixed[o] = 0.f;

        for (int c0 = 0; c0 < 32; c0 += 4) {
            {
                int c = c0 + scc;
                int h = c & 15;
                const uint32_t* src = (c < 16) ? q32A : q32F;
                int n = n0 + sr;
                float4 f0 = make_float4(0.f,0.f,0.f,0.f), f1 = f0, f2 = f0;
                if (n < NN) {
                    const uint2* g = (const uint2*)(src + ((size_t)h * NN + n) * 24 + sq * 6);
                    uint2 w0 = g[0], w1 = g[1], w2 = g[2];
                    f0 = make_float4(bf_lo(w0.x), bf_hi(w0.x), bf_lo(w0.y), bf_hi(w0.y));
                    f1 = make_float4(bf_lo(w1.x), bf_hi(w1.x), bf_lo(w1.y), bf_hi(w1.y));
                    f2 = make_float4(bf_lo(w2.x), bf_hi(w2.x), bf_lo(w2.y), bf_hi(w2.y));
                }
                float4* dst = &qch4[(scc * 16 + sr) * 13 + sq * 3];
                dst[0] = f0; dst[1] = f1; dst[2] = f2;
            }
            {
                int c = c0 + scc;
                int h = c & 15;
                const uint32_t* src = (c < 16) ? k32A : k32F;
                int m = m0 + sr;
                float4 f0 = make_float4(0.f,0.f,0.f,0.f), f1 = f0, f2 = f0;
                if (m < NN) {
                    const uint2* g = (const uint2*)(src + ((size_t)h * NN + m) * 24 + sq * 6);
                    uint2 w0 = g[0], w1 = g[1], w2 = g[2];
                    f0 = make_float4(bf_lo(w0.x), bf_hi(w0.x), bf_lo(w0.y), bf_hi(w0.y));
                    f1 = make_float4(bf_lo(w1.x), bf_hi(w1.x), bf_lo(w1.y), bf_hi(w1.y));
                    f2 = make_float4(bf_lo(w2.x), bf_hi(w2.x), bf_lo(w2.y), bf_hi(w2.y));
                }
                float4* dst = &kch4[(scc * 16 + sr) * 13 + sq * 3];
                dst[0] = f0; dst[1] = f1; dst[2] = f2;
            }
            __syncthreads();

#pragma unroll
            for (int cc = 0; cc < 4; ++cc) {
                const float4* qp = &qch4[(cc * 16 + rr) * 13];
                const float4* kp = &kch4[(cc * 16 + u) * 13];
                float s0 = 0.f, s1 = 0.f, s2 = 0.f, s3 = 0.f;
#pragma unroll
                for (int i = 0; i < 12; ++i) {
                    float4 a = qp[i], bb4 = kp[i];
                    s0 += a.x * bb4.x; s1 += a.y * bb4.y;
                    s2 += a.z * bb4.z; s3 += a.w * bb4.w;
                }
                float s = (s0 + s1) + (s2 + s3);
                int c = c0 + cc;
                float p = __expf(s * scale) * invS_l[c * 16 + rr];
                const float4* cwp = (const float4*)&cwT[c * 16];
#pragma unroll
                for (int j = 0; j < 4; ++j) {
                    float4 w4 = cwp[j];
                    mixed[4 * j + 0] += w4.x * p;
                    mixed[4 * j + 1] += w4.y * p;
                    mixed[4 * j + 2] += w4.z * p;
                    mixed[4 * j + 3] += w4.w * p;
                }
            }
            __syncthreads();
        }

        // ---- e = exp(mixed + cb) ----
        {
            int m = m0 + u;
            float* ep = &e_lds[(rr * 16 + u) * 17];
            if (m < NN) {
#pragma unroll
                for (int o = 0; o < 16; ++o) ep[o] = __expf(mixed[o] + cb_l[o]);
            } else {
#pragma unroll
                for (int o = 0; o < 16; ++o) ep[o] = 0.f;
            }
        }
        __syncthreads();

        // ---- PV ----
#pragma unroll
        for (int mm = 0; mm < 16; ++mm) {
            float ev = e_lds[(rr * 16 + mm) * 17 + u];
            denom += ev;
            const uint4* vp = &vt4[u * 113 + mm * 7];
#pragma unroll
            for (int i = 0; i < 6; ++i) {
                uint4 vv = vp[i];
                acc[i * 8 + 0] += ev * bf_lo(vv.x); acc[i * 8 + 1] += ev * bf_hi(vv.x);
                acc[i * 8 + 2] += ev * bf_lo(vv.y); acc[i * 8 + 3] += ev * bf_hi(vv.y);
                acc[i * 8 + 4] += ev * bf_lo(vv.z); acc[i * 8 + 5] += ev * bf_hi(vv.z);
                acc[i * 8 + 6] += ev * bf_lo(vv.w); acc[i * 8 + 7] += ev * bf_hi(vv.w);
            }
        }
        __syncthreads();
    }

    int n = n0 + rr;
    if (n < NN) {
        if (NS == 1) {
            float inv = 1.0f / denom;
            float4* wp = (float4*)(weighted + ((size_t)b * NN + n) * DD + u * HD);
#pragma unroll
            for (int i = 0; i < 12; ++i)
                wp[i] = make_float4(acc[4*i]*inv, acc[4*i+1]*inv, acc[4*i+2]*inv, acc[4*i+3]*inv);
        } else {
            float4* np = (float4*)(pnum + (((size_t)slice * BB + b) * NN + n) * DD + u * HD);
#pragma unroll
            for (int i = 0; i < 12; ++i)
                np[i] = make_float4(acc[4*i], acc[4*i+1], acc[4*i+2], acc[4*i+3]);
            pden[(((size_t)slice * BB + b) * NN + n) * 16 + u] = denom;
        }
    }
}

// ---------------------------------------------------------------------------
// K3b: reduce slices + divide.
// ---------------------------------------------------------------------------
__global__ __launch_bounds__(256) void k_red(
    const float* __restrict__ pnum, const float* __restrict__ pden,
    float* __restrict__ weighted, int NS)
{
    int col = blockIdx.x * 256 + threadIdx.x;   // 0..767
    int bn  = blockIdx.y;                       // 0..4615
    int o   = (col * 1366) >> 16;               // col / 48
    float sn = 0.f, sd = 0.f;
    for (int s = 0; s < NS; ++s) {
        sn += pnum[((size_t)s * M1 + bn) * DD + col];
        sd += pden[((size_t)s * M1 + bn) * 16 + o];
    }
    weighted[(size_t)bn * DD + col] = sn / sd;
}

// ---------------------------------------------------------------------------
// K4: out = weighted @ proj_w^T + proj_b.
// ---------------------------------------------------------------------------
__global__ __launch_bounds__(256) void k_proj(
    const float* __restrict__ A, const float* __restrict__ w, const float* __restrict__ bias,
    float* __restrict__ out)
{
    __shared__ float As[16][65];
    __shared__ float Bs[16][65];
    const int t    = threadIdx.x;
    const int m0   = blockIdx.x * 64;
    const int n0   = blockIdx.y * 64;
    const int lrow = t >> 2;
    const int lk4  = (t & 3) << 2;
    const int tm   = (t & 15) << 2;
    const int tn   = (t >> 4) << 2;
    float acc[4][4] = {};

    for (int k0 = 0; k0 < DD; k0 += 16) {
        int gm = m0 + lrow;
        float4 av = make_float4(0.f, 0.f, 0.f, 0.f);
        if (gm < M1) av = *reinterpret_cast<const float4*>(A + (size_t)gm * DD + k0 + lk4);
        As[lk4 + 0][lrow] = av.x; As[lk4 + 1][lrow] = av.y;
        As[lk4 + 2][lrow] = av.z; As[lk4 + 3][lrow] = av.w;
        int gj = n0 + lrow;
        float4 bv = *reinterpret_cast<const float4*>(w + (size_t)gj * DD + k0 + lk4);
        Bs[lk4 + 0][lrow] = bv.x; Bs[lk4 + 1][lrow] = bv.y;
        Bs[lk4 + 2][lrow] = bv.z; Bs[lk4 + 3][lrow] = bv.w;
        __syncthreads();
#pragma unroll
        for (int k = 0; k < 16; ++k) {
            float a[4], b[4];
#pragma unroll
            for (int i = 0; i < 4; ++i) a[i] = As[k][tm + i];
#pragma unroll
            for (int j = 0; j < 4; ++j) b[j] = Bs[k][tn + j];
#pragma unroll
            for (int i = 0; i < 4; ++i)
#pragma unroll
                for (int j = 0; j < 4; ++j)
                    acc[i][j] += a[i] * b[j];
        }
        __syncthreads();
    }

#pragma unroll
    for (int i = 0; i < 4; ++i) {
        int gm = m0 + tm + i;
        if (gm >= M1) continue;
#pragma unroll
        for (int j = 0; j < 4; ++j) {
            int gn = n0 + tn + j;
            out[(size_t)gm * DD + gn] = acc[i][j] + bias[gn];
        }
    }
}

extern "C" void kernel_launch(void* const* d_in, const int* in_sizes, int n_in,
                              void* d_out, int out_size, void* d_ws, size_t ws_size,
                              hipStream_t stream) {
    const float* x      = (const float*)d_in[0];
    const float* xf     = (const float*)d_in[1];
    const float* qkv_w  = (const float*)d_in[2];
    const float* qkv_b  = (const float*)d_in[3];
    const float* conv_w = (const float*)d_in[4];
    const float* conv_b = (const float*)d_in[5];
    const float* proj_w = (const float*)d_in[6];
    const float* proj_b = (const float*)d_in[7];
    float* out = (float*)d_out;

    const size_t SZ = (size_t)BB * HH * NN * HD;   // 3,545,088 elems
    uint16_t* qA = (uint16_t*)d_ws;
    uint16_t* kA = qA + SZ;
    uint16_t* vA = kA + SZ;
    uint16_t* qF = vA + SZ;
    uint16_t* kF = qF + SZ;
    float* Ssum     = (float*)(kF + SZ);
    float* weighted = Ssum + (size_t)BB * CC * NN;
    float* pnum     = weighted + (size_t)M1 * DD;
    const size_t base_bytes  = (size_t)(5 * SZ) * 2 + ((size_t)BB * CC * NN + (size_t)M1 * DD) * 4;
    const size_t slice_bytes = ((size_t)M1 * DD + (size_t)M1 * 16) * 4;
    int NS = 1;
    if (ws_size >= base_bytes + 4 * slice_bytes)      NS = 4;
    else if (ws_size >= base_bytes + 2 * slice_bytes) NS = 2;
    float* pden = pnum + (size_t)NS * M1 * DD;

    k_qkv  <<<dim3(145, 36, 1), 256, 0, stream>>>(x, xf, qkv_w, qkv_b, qA, kA, vA, qF, kF);
    k_sum1 <<<dim3(19, 32, 8),  256, 0, stream>>>(qA, kA, qF, kF, Ssum);
    k_mix_pv<<<dim3(37 * 8 * NS), 256, 0, stream>>>(qA, kA, vA, qF, kF, Ssum, conv_w, conv_b,
                                                    weighted, pnum, pden, NS);
    if (NS > 1)
        k_red<<<dim3(3, M1), 256, 0, stream>>>(pnum, pden, weighted, NS);
    k_proj <<<dim3(73, 12, 1),  256, 0, stream>>>(weighted, proj_w, proj_b, out);
}

// Round 5
// 1158.122 us; speedup vs baseline: 4.2004x; 2.1077x over previous
//
#include <hip/hip_runtime.h>
#include <stdint.h>

#define BB 8
#define NN 577
#define DD 768
#define HH 16
#define HD 48
#define CC 32
#define M1 4616   /* B*N  */
#define M2 9232   /* 2*B*N */

typedef __attribute__((ext_vector_type(8))) short bf16x8;
typedef __attribute__((ext_vector_type(4))) float f32x4;

static __device__ __forceinline__ float bf_lo(uint32_t u){ return __uint_as_float(u << 16); }
static __device__ __forceinline__ float bf_hi(uint32_t u){ return __uint_as_float(u & 0xffff0000u); }
static __device__ __forceinline__ uint16_t f2bf(float f){
    uint32_t u = __float_as_uint(f);
    return (uint16_t)((u + 0x7fffu + ((u >> 16) & 1u)) >> 16);
}
static __device__ __forceinline__ uint32_t pk2(float lo, float hi){
    return ((uint32_t)f2bf(hi) << 16) | (uint32_t)f2bf(lo);
}
static __device__ __forceinline__ bf16x8 ldfrag(const uint16_t* p){
    return *reinterpret_cast<const bf16x8*>(p);
}

// ---------------------------------------------------------------------------
// K1: qkv = [x; x_freq] @ qkv_w^T + qkv_b  via bf16 MFMA, scatter to head-layout.
//     BM=64 BN=64 BK=32, 4 waves in 2x2 quadrants of 32x32 (2x2 16x16 frags).
// ---------------------------------------------------------------------------
__global__ __launch_bounds__(256) void k_qkv(
    const float* __restrict__ x, const float* __restrict__ xf,
    const float* __restrict__ w, const float* __restrict__ bias,
    uint16_t* __restrict__ qA, uint16_t* __restrict__ kA, uint16_t* __restrict__ vA,
    uint16_t* __restrict__ qF, uint16_t* __restrict__ kF)
{
    __shared__ uint16_t As[64 * 40];   // [64 m][32 k] bf16, stride 40 (pad)
    __shared__ uint16_t Bs[64 * 40];   // [64 n][32 k]
    const int t    = threadIdx.x;
    const int m0   = blockIdx.x * 64;
    const int n0   = blockIdx.y * 64;
    const int lane = t & 63;
    const int wid  = t >> 6;
    const int wm   = wid >> 1;
    const int wn   = wid & 1;
    const int r    = lane & 15;
    const int g    = lane >> 4;

    f32x4 acc[2][2];
#pragma unroll
    for (int i = 0; i < 2; ++i)
#pragma unroll
        for (int j = 0; j < 2; ++j) acc[i][j] = (f32x4){0.f, 0.f, 0.f, 0.f};

    const int srow = t & 63;
    const int seg  = t >> 6;

    for (int k0 = 0; k0 < DD; k0 += 32) {
        // stage A (x/xf f32 -> bf16)
        {
            int gm = m0 + srow;
            uint4 pk4 = make_uint4(0u, 0u, 0u, 0u);
            if (gm < M2) {
                const float* src = (gm < M1) ? (x + (size_t)gm * DD) : (xf + (size_t)(gm - M1) * DD);
                float4 a = *reinterpret_cast<const float4*>(src + k0 + seg * 8);
                float4 b = *reinterpret_cast<const float4*>(src + k0 + seg * 8 + 4);
                pk4 = make_uint4(pk2(a.x, a.y), pk2(a.z, a.w), pk2(b.x, b.y), pk2(b.z, b.w));
            }
            *reinterpret_cast<uint4*>(&As[srow * 40 + seg * 8]) = pk4;
            const float* wsrc = w + (size_t)(n0 + srow) * DD + k0 + seg * 8;
            float4 a = *reinterpret_cast<const float4*>(wsrc);
            float4 b = *reinterpret_cast<const float4*>(wsrc + 4);
            *reinterpret_cast<uint4*>(&Bs[srow * 40 + seg * 8]) =
                make_uint4(pk2(a.x, a.y), pk2(a.z, a.w), pk2(b.x, b.y), pk2(b.z, b.w));
        }
        __syncthreads();
        bf16x8 af[2], bf[2];
#pragma unroll
        for (int i = 0; i < 2; ++i)
            af[i] = *reinterpret_cast<const bf16x8*>(&As[(wm * 32 + i * 16 + r) * 40 + g * 8]);
#pragma unroll
        for (int j = 0; j < 2; ++j)
            bf[j] = *reinterpret_cast<const bf16x8*>(&Bs[(wn * 32 + j * 16 + r) * 40 + g * 8]);
#pragma unroll
        for (int i = 0; i < 2; ++i)
#pragma unroll
            for (int j = 0; j < 2; ++j)
                acc[i][j] = __builtin_amdgcn_mfma_f32_16x16x32_bf16(af[i], bf[j], acc[i][j], 0, 0, 0);
        __syncthreads();
    }

    // epilogue: D rows = g*4+reg, cols = r; add bias, scatter to head layout
#pragma unroll
    for (int j = 0; j < 2; ++j) {
        int gn   = n0 + wn * 32 + j * 16 + r;
        float bv = bias[gn];
        int part = gn / DD;
        int dcol = gn % DD;
        int hh   = dcol / HD;
        int dd   = dcol % HD;
        uint16_t* dst;
        bool skip_f = false;
        uint16_t* dstA = (part == 0) ? qA : (part == 1) ? kA : vA;
        uint16_t* dstF = (part == 0) ? qF : (part == 1) ? kF : (uint16_t*)nullptr;
        if (part == 2) skip_f = true;
#pragma unroll
        for (int i = 0; i < 2; ++i) {
#pragma unroll
            for (int reg = 0; reg < 4; ++reg) {
                int gm = m0 + wm * 32 + i * 16 + g * 4 + reg;
                if (gm >= M2) continue;
                float val = acc[i][j][reg] + bv;
                int srcb = (gm >= M1) ? 1 : 0;
                int row  = gm - srcb * M1;
                int bb   = row / NN;
                int nn   = row % NN;
                if (srcb == 0) dst = dstA;
                else { if (skip_f) continue; dst = dstF; }
                dst[(((size_t)bb * HH + hh) * NN + nn) * HD + dd] = f2bf(val);
            }
        }
    }
}

// ---------------------------------------------------------------------------
// K2: softmax-1 denominators via MFMA (swapped: D[m][r] = K·Q^T). LDS-free.
//     grid 1D = 8b * 32c * 10 row-groups; block = 4 waves x 16 rows.
// ---------------------------------------------------------------------------
__global__ __launch_bounds__(256) void k_sum1(
    const uint16_t* __restrict__ qA, const uint16_t* __restrict__ kA,
    const uint16_t* __restrict__ qF, const uint16_t* __restrict__ kF,
    float* __restrict__ Ssum)
{
    const float scale = 0.14433756729740643f; // 48^-0.5
    const int id   = blockIdx.x;
    const int b    = id & 7;
    const int rest = id >> 3;
    const int c    = rest & 31;
    const int rt   = rest >> 5;
    const int t    = threadIdx.x;
    const int lane = t & 63;
    const int wid  = t >> 6;
    const int r    = lane & 15;
    const int g    = lane >> 4;
    const int h    = c & 15;

    const uint16_t* qb = (c < 16) ? qA : qF;
    const uint16_t* kb = (c < 16) ? kA : kF;
    const size_t hb = (size_t)(b * HH + h) * NN;

    const int nq = rt * 64 + wid * 16 + r;
    bf16x8 z = {0, 0, 0, 0, 0, 0, 0, 0};
    bf16x8 qf0 = z, qf1 = z;
    if (nq < NN) {
        const uint16_t* qrow = qb + (hb + nq) * 48;
        qf0 = ldfrag(qrow + g * 8);
        if (g < 2) qf1 = ldfrag(qrow + 32 + g * 8);
    }

    float sum = 0.f;
#pragma unroll 2
    for (int mt = 0; mt < 37; ++mt) {
        const int m0 = mt * 16;
        const uint16_t* krow = kb + (hb + (size_t)(m0 + r)) * 48;  // OOB rows stay inside d_ws
        bf16x8 kf0 = ldfrag(krow + g * 8);
        bf16x8 kf1 = z;
        if (g < 2) kf1 = ldfrag(krow + 32 + g * 8);
        f32x4 d = {0.f, 0.f, 0.f, 0.f};
        d = __builtin_amdgcn_mfma_f32_16x16x32_bf16(kf0, qf0, d, 0, 0, 0);
        d = __builtin_amdgcn_mfma_f32_16x16x32_bf16(kf1, qf1, d, 0, 0, 0);
#pragma unroll
        for (int reg = 0; reg < 4; ++reg) {
            int m = m0 + g * 4 + reg;
            if (m < NN) sum += __expf(d[reg] * scale);
        }
    }
    sum += __shfl_xor(sum, 16, 64);
    sum += __shfl_xor(sum, 32, 64);
    if (g == 0 && nq < NN) Ssum[((size_t)b * CC + c) * NN + nq] = sum;
}

// ---------------------------------------------------------------------------
// K3 v4: fused scores(MFMA) -> softmax1 -> conv mix -> exp -> PV.
//   - swapped MFMA D[m][r]: col = q-row r (lane-local) -> invS in 8 regs
//   - Q/K frags loaded straight from global (L2, XCD-pinned); no Q/K LDS
//   - per-wave c-split (8 channels); bf16 mix partials reduced through LDS
//   - e stored bf16; PV unchanged VALU
//   - conv_b dropped: constant per (o,row) cancels in softmax-2
// ---------------------------------------------------------------------------
__global__ __launch_bounds__(256) void k_mix_pv(
    const uint16_t* __restrict__ qA, const uint16_t* __restrict__ kA, const uint16_t* __restrict__ vA,
    const uint16_t* __restrict__ qF, const uint16_t* __restrict__ kF,
    const float* __restrict__ Ssum, const float* __restrict__ conv_w,
    float* __restrict__ weighted, float* __restrict__ pnum, float* __restrict__ pden, int NS)
{
    __shared__ uint32_t mixp32[4 * 16 * 16 * 8];   // 32 KB  [wave][m][r][8 u32 = 16 o bf16]
    __shared__ uint32_t e32[16 * 16 * 12];         // 12 KB  [r][m][12 u32 = 16 o bf16 + pad]
    __shared__ __align__(16) uint4 vt4[16 * 113];  // 28.9 KB [o][m] v tile (bf16 packed)
    __shared__ float cwL[512];                     //  2 KB  cwL[c][o]
    const float scale = 0.14433756729740643f;

    const int t     = threadIdx.x;
    const int id    = blockIdx.x;
    const int b     = id & 7;
    const int rest  = id >> 3;
    const int slice = rest % NS;
    const int n0    = (rest / NS) * 16;
    const int lane  = t & 63;
    const int wid   = t >> 6;
    const int r     = lane & 15;
    const int g     = lane >> 4;

    for (int i = t; i < 512; i += 256) {
        int c = i >> 4, o = i & 15;
        cwL[i] = conv_w[o * 32 + c];
    }

    // hoisted per-lane invS for this wave's 8 channels at its q-row r
    float invS_r[8];
#pragma unroll
    for (int cc = 0; cc < 8; ++cc) {
        int c = wid * 8 + cc;
        int n = n0 + r;
        invS_r[cc] = (n < NN) ? 1.0f / Ssum[((size_t)b * CC + c) * NN + n] : 0.f;
    }

    const uint32_t* v32 = (const uint32_t*)vA + (size_t)b * HH * NN * 24;
    const int rr = t >> 4;   // PV: q-row
    const int u  = t & 15;   // PV: head
    const int vo = t >> 4;   // V-stage: head
    const int vm = t & 15;   // V-stage: m
    float acc[48] = {};
    float denom = 0.f;
    bf16x8 z = {0, 0, 0, 0, 0, 0, 0, 0};
    __syncthreads();

    for (int mt = slice; mt < 37; mt += NS) {
        const int m0 = mt * 16;

        // ---- V tile: issue global loads early, LDS writes at end of phase A ----
        uint4 vreg[6];
        {
            int m = m0 + vm;
            if (m < NN) {
                const uint4* gv = (const uint4*)(v32 + ((size_t)vo * NN + m) * 24);
#pragma unroll
                for (int i = 0; i < 6; ++i) vreg[i] = gv[i];
            } else {
#pragma unroll
                for (int i = 0; i < 6; ++i) vreg[i] = make_uint4(0u, 0u, 0u, 0u);
            }
        }

        // ---- Phase A: MFMA scores + partial mix for this wave's 8 channels ----
        float mixed[64];   // [o][mreg]
#pragma unroll
        for (int i = 0; i < 64; ++i) mixed[i] = 0.f;

#pragma unroll
        for (int cc = 0; cc < 8; ++cc) {
            const int c = wid * 8 + cc;
            const int h = c & 15;
            const uint16_t* qb = (c < 16) ? qA : qF;
            const uint16_t* kb = (c < 16) ? kA : kF;
            const size_t hb = (size_t)(b * HH + h) * NN;

            bf16x8 qf0 = z, qf1 = z;
            {
                int nq = n0 + r;
                if (nq < NN) {
                    const uint16_t* qrow = qb + (hb + nq) * 48;
                    qf0 = ldfrag(qrow + g * 8);
                    if (g < 2) qf1 = ldfrag(qrow + 32 + g * 8);
                }
            }
            const uint16_t* krow = kb + (hb + (size_t)(m0 + r)) * 48; // OOB stays in d_ws
            bf16x8 kf0 = ldfrag(krow + g * 8);
            bf16x8 kf1 = z;
            if (g < 2) kf1 = ldfrag(krow + 32 + g * 8);

            f32x4 d = {0.f, 0.f, 0.f, 0.f};
            d = __builtin_amdgcn_mfma_f32_16x16x32_bf16(kf0, qf0, d, 0, 0, 0);
            d = __builtin_amdgcn_mfma_f32_16x16x32_bf16(kf1, qf1, d, 0, 0, 0);

            float pu[4];
#pragma unroll
            for (int reg = 0; reg < 4; ++reg)
                pu[reg] = __expf(d[reg] * scale) * invS_r[cc];
#pragma unroll
            for (int oq = 0; oq < 4; ++oq) {
                float4 w4 = *reinterpret_cast<const float4*>(&cwL[c * 16 + oq * 4]);
#pragma unroll
                for (int reg = 0; reg < 4; ++reg) {
                    mixed[(oq * 4 + 0) * 4 + reg] += w4.x * pu[reg];
                    mixed[(oq * 4 + 1) * 4 + reg] += w4.y * pu[reg];
                    mixed[(oq * 4 + 2) * 4 + reg] += w4.z * pu[reg];
                    mixed[(oq * 4 + 3) * 4 + reg] += w4.w * pu[reg];
                }
            }
        }

        // write bf16 partials: mixp[wid][m=g*4+reg][r][16 o]
#pragma unroll
        for (int reg = 0; reg < 4; ++reg) {
            int base = (((wid * 16 + (g * 4 + reg)) * 16) + r) * 8;
            uint4 A0 = make_uint4(pk2(mixed[0 * 4 + reg],  mixed[1 * 4 + reg]),
                                  pk2(mixed[2 * 4 + reg],  mixed[3 * 4 + reg]),
                                  pk2(mixed[4 * 4 + reg],  mixed[5 * 4 + reg]),
                                  pk2(mixed[6 * 4 + reg],  mixed[7 * 4 + reg]));
            uint4 A1 = make_uint4(pk2(mixed[8 * 4 + reg],  mixed[9 * 4 + reg]),
                                  pk2(mixed[10 * 4 + reg], mixed[11 * 4 + reg]),
                                  pk2(mixed[12 * 4 + reg], mixed[13 * 4 + reg]),
                                  pk2(mixed[14 * 4 + reg], mixed[15 * 4 + reg]));
            *reinterpret_cast<uint4*>(&mixp32[base])     = A0;
            *reinterpret_cast<uint4*>(&mixp32[base + 4]) = A1;
        }
        // V tile LDS write (loads were in flight during phase A)
#pragma unroll
        for (int i = 0; i < 6; ++i) vt4[vo * 113 + vm * 7 + i] = vreg[i];
        __syncthreads();

        // ---- Phase B: reduce partials over 4 waves, exp -> e (bf16) ----
        {
            const int bm = t >> 4, br = t & 15;
            float tot[16];
#pragma unroll
            for (int o = 0; o < 16; ++o) tot[o] = 0.f;
#pragma unroll
            for (int w = 0; w < 4; ++w) {
                int base = (((w * 16 + bm) * 16) + br) * 8;
                uint4 A0 = *reinterpret_cast<const uint4*>(&mixp32[base]);
                uint4 A1 = *reinterpret_cast<const uint4*>(&mixp32[base + 4]);
                tot[0]  += bf_lo(A0.x); tot[1]  += bf_hi(A0.x);
                tot[2]  += bf_lo(A0.y); tot[3]  += bf_hi(A0.y);
                tot[4]  += bf_lo(A0.z); tot[5]  += bf_hi(A0.z);
                tot[6]  += bf_lo(A0.w); tot[7]  += bf_hi(A0.w);
                tot[8]  += bf_lo(A1.x); tot[9]  += bf_hi(A1.x);
                tot[10] += bf_lo(A1.y); tot[11] += bf_hi(A1.y);
                tot[12] += bf_lo(A1.z); tot[13] += bf_hi(A1.z);
                tot[14] += bf_lo(A1.w); tot[15] += bf_hi(A1.w);
            }
            bool valid = (m0 + bm) < NN;
            float ev[16];
#pragma unroll
            for (int o = 0; o < 16; ++o) ev[o] = valid ? __expf(tot[o]) : 0.f;
            int base = (br * 16 + bm) * 12;
            *reinterpret_cast<uint4*>(&e32[base]) =
                make_uint4(pk2(ev[0], ev[1]), pk2(ev[2], ev[3]), pk2(ev[4], ev[5]), pk2(ev[6], ev[7]));
            *reinterpret_cast<uint4*>(&e32[base + 4]) =
                make_uint4(pk2(ev[8], ev[9]), pk2(ev[10], ev[11]), pk2(ev[12], ev[13]), pk2(ev[14], ev[15]));
        }
        __syncthreads();

        // ---- Phase C: PV ----
        const uint16_t* e16 = (const uint16_t*)e32;
#pragma unroll
        for (int mm = 0; mm < 16; ++mm) {
            float ev = __uint_as_float((uint32_t)e16[(rr * 16 + mm) * 24 + u] << 16);
            denom += ev;
            const uint4* vp = &vt4[u * 113 + mm * 7];
#pragma unroll
            for (int i = 0; i < 6; ++i) {
                uint4 vv = vp[i];
                acc[i * 8 + 0] += ev * bf_lo(vv.x); acc[i * 8 + 1] += ev * bf_hi(vv.x);
                acc[i * 8 + 2] += ev * bf_lo(vv.y); acc[i * 8 + 3] += ev * bf_hi(vv.y);
                acc[i * 8 + 4] += ev * bf_lo(vv.z); acc[i * 8 + 5] += ev * bf_hi(vv.z);
                acc[i * 8 + 6] += ev * bf_lo(vv.w); acc[i * 8 + 7] += ev * bf_hi(vv.w);
            }
        }
        __syncthreads();
    }

    int n = n0 + rr;
    if (n < NN) {
        if (NS == 1) {
            float inv = 1.0f / denom;
            float4* wp = (float4*)(weighted + ((size_t)b * NN + n) * DD + u * HD);
#pragma unroll
            for (int i = 0; i < 12; ++i)
                wp[i] = make_float4(acc[4*i]*inv, acc[4*i+1]*inv, acc[4*i+2]*inv, acc[4*i+3]*inv);
        } else {
            float4* np = (float4*)(pnum + (((size_t)slice * BB + b) * NN + n) * DD + u * HD);
#pragma unroll
            for (int i = 0; i < 12; ++i)
                np[i] = make_float4(acc[4*i], acc[4*i+1], acc[4*i+2], acc[4*i+3]);
            pden[(((size_t)slice * BB + b) * NN + n) * 16 + u] = denom;
        }
    }
}

// ---------------------------------------------------------------------------
// K3b: reduce slices + divide.
// ---------------------------------------------------------------------------
__global__ __launch_bounds__(256) void k_red(
    const float* __restrict__ pnum, const float* __restrict__ pden,
    float* __restrict__ weighted, int NS)
{
    int col = blockIdx.x * 256 + threadIdx.x;   // 0..767
    int bn  = blockIdx.y;                       // 0..4615
    int o   = (col * 1366) >> 16;               // col / 48
    float sn = 0.f, sd = 0.f;
    for (int s = 0; s < NS; ++s) {
        sn += pnum[((size_t)s * M1 + bn) * DD + col];
        sd += pden[((size_t)s * M1 + bn) * 16 + o];
    }
    weighted[(size_t)bn * DD + col] = sn / sd;
}

// ---------------------------------------------------------------------------
// K4: out = weighted @ proj_w^T + proj_b.  fp32 (precision headroom).
// ---------------------------------------------------------------------------
__global__ __launch_bounds__(256) void k_proj(
    const float* __restrict__ A, const float* __restrict__ w, const float* __restrict__ bias,
    float* __restrict__ out)
{
    __shared__ float As[16][65];
    __shared__ float Bs[16][65];
    const int t    = threadIdx.x;
    const int m0   = blockIdx.x * 64;
    const int n0   = blockIdx.y * 64;
    const int lrow = t >> 2;
    const int lk4  = (t & 3) << 2;
    const int tm   = (t & 15) << 2;
    const int tn   = (t >> 4) << 2;
    float acc[4][4] = {};

    for (int k0 = 0; k0 < DD; k0 += 16) {
        int gm = m0 + lrow;
        float4 av = make_float4(0.f, 0.f, 0.f, 0.f);
        if (gm < M1) av = *reinterpret_cast<const float4*>(A + (size_t)gm * DD + k0 + lk4);
        As[lk4 + 0][lrow] = av.x; As[lk4 + 1][lrow] = av.y;
        As[lk4 + 2][lrow] = av.z; As[lk4 + 3][lrow] = av.w;
        int gj = n0 + lrow;
        float4 bv = *reinterpret_cast<const float4*>(w + (size_t)gj * DD + k0 + lk4);
        Bs[lk4 + 0][lrow] = bv.x; Bs[lk4 + 1][lrow] = bv.y;
        Bs[lk4 + 2][lrow] = bv.z; Bs[lk4 + 3][lrow] = bv.w;
        __syncthreads();
#pragma unroll
        for (int k = 0; k < 16; ++k) {
            float a[4], b[4];
#pragma unroll
            for (int i = 0; i < 4; ++i) a[i] = As[k][tm + i];
#pragma unroll
            for (int j = 0; j < 4; ++j) b[j] = Bs[k][tn + j];
#pragma unroll
            for (int i = 0; i < 4; ++i)
#pragma unroll
                for (int j = 0; j < 4; ++j)
                    acc[i][j] += a[i] * b[j];
        }
        __syncthreads();
    }

#pragma unroll
    for (int i = 0; i < 4; ++i) {
        int gm = m0 + tm + i;
        if (gm >= M1) continue;
#pragma unroll
        for (int j = 0; j < 4; ++j) {
            int gn = n0 + tn + j;
            out[(size_t)gm * DD + gn] = acc[i][j] + bias[gn];
        }
    }
}

extern "C" void kernel_launch(void* const* d_in, const int* in_sizes, int n_in,
                              void* d_out, int out_size, void* d_ws, size_t ws_size,
                              hipStream_t stream) {
    const float* x      = (const float*)d_in[0];
    const float* xf     = (const float*)d_in[1];
    const float* qkv_w  = (const float*)d_in[2];
    const float* qkv_b  = (const float*)d_in[3];
    const float* conv_w = (const float*)d_in[4];
    const float* proj_w = (const float*)d_in[6];
    const float* proj_b = (const float*)d_in[7];
    float* out = (float*)d_out;

    const size_t SZ = (size_t)BB * HH * NN * HD;   // 3,545,088 elems
    uint16_t* qA = (uint16_t*)d_ws;
    uint16_t* kA = qA + SZ;
    uint16_t* vA = kA + SZ;
    uint16_t* qF = vA + SZ;
    uint16_t* kF = qF + SZ;
    float* Ssum     = (float*)(kF + SZ);
    float* weighted = Ssum + (size_t)BB * CC * NN;
    float* pnum     = weighted + (size_t)M1 * DD;
    const size_t base_bytes  = (size_t)(5 * SZ) * 2 + ((size_t)BB * CC * NN + (size_t)M1 * DD) * 4;
    const size_t slice_bytes = ((size_t)M1 * DD + (size_t)M1 * 16) * 4;
    int NS = 1;
    if (ws_size >= base_bytes + 4 * slice_bytes)      NS = 4;
    else if (ws_size >= base_bytes + 2 * slice_bytes) NS = 2;
    float* pden = pnum + (size_t)NS * M1 * DD;

    k_qkv  <<<dim3(145, 36, 1), 256, 0, stream>>>(x, xf, qkv_w, qkv_b, qA, kA, vA, qF, kF);
    k_sum1 <<<dim3(8 * 32 * 10), 256, 0, stream>>>(qA, kA, qF, kF, Ssum);
    k_mix_pv<<<dim3(8 * NS * 37), 256, 0, stream>>>(qA, kA, vA, qF, kF, Ssum, conv_w,
                                                    weighted, pnum, pden, NS);
    if (NS > 1)
        k_red<<<dim3(3, M1), 256, 0, stream>>>(pnum, pden, weighted, NS);
    k_proj <<<dim3(73, 12, 1),  256, 0, stream>>>(weighted, proj_w, proj_b, out);
}

// Round 9
// 866.177 us; speedup vs baseline: 5.6162x; 1.3371x over previous
//
#include <hip/hip_runtime.h>
#include <stdint.h>

#define BB 8
#define NN 577
#define DD 768
#define HH 16
#define HD 48
#define CC 32
#define M1 4616   /* B*N  */
#define M2 9232   /* 2*B*N */
#define NP 608    /* padded N for transposed-V layout (38 tiles of 16) */
#define SRE 36    /* e_a row stride in u16 (16B-aligned frags, spread banks) */

typedef __attribute__((ext_vector_type(8))) short bf16x8;
typedef __attribute__((ext_vector_type(4))) float f32x4;

static __device__ __forceinline__ float bf_lo(uint32_t u){ return __uint_as_float(u << 16); }
static __device__ __forceinline__ float bf_hi(uint32_t u){ return __uint_as_float(u & 0xffff0000u); }
static __device__ __forceinline__ uint16_t f2bf(float f){
    uint32_t u = __float_as_uint(f);
    return (uint16_t)((u + 0x7fffu + ((u >> 16) & 1u)) >> 16);
}
static __device__ __forceinline__ uint32_t pk2(float lo, float hi){
    return ((uint32_t)f2bf(hi) << 16) | (uint32_t)f2bf(lo);
}
static __device__ __forceinline__ bf16x8 ldfrag(const uint16_t* p){
    return *reinterpret_cast<const bf16x8*>(p);
}

// ---------------------------------------------------------------------------
// K1: qkv = [x; x_freq] @ qkv_w^T + qkv_b  via bf16 MFMA.
//     q/k scattered to [b][h][n][48]; v scattered TRANSPOSED to [b][h][d][NP].
// ---------------------------------------------------------------------------
__global__ __launch_bounds__(256) void k_qkv(
    const float* __restrict__ x, const float* __restrict__ xf,
    const float* __restrict__ w, const float* __restrict__ bias,
    uint16_t* __restrict__ qA, uint16_t* __restrict__ kA, uint16_t* __restrict__ vT,
    uint16_t* __restrict__ qF, uint16_t* __restrict__ kF)
{
    __shared__ uint16_t As[64 * 40];   // [64 m][32 k] bf16, stride 40 (pad)
    __shared__ uint16_t Bs[64 * 40];   // [64 n][32 k]
    const int t    = threadIdx.x;
    const int m0   = blockIdx.x * 64;
    const int n0   = blockIdx.y * 64;
    const int lane = t & 63;
    const int wid  = t >> 6;
    const int wm   = wid >> 1;
    const int wn   = wid & 1;
    const int r    = lane & 15;
    const int g    = lane >> 4;

    f32x4 acc[2][2];
#pragma unroll
    for (int i = 0; i < 2; ++i)
#pragma unroll
        for (int j = 0; j < 2; ++j) acc[i][j] = (f32x4){0.f, 0.f, 0.f, 0.f};

    const int srow = t & 63;
    const int seg  = t >> 6;

    for (int k0 = 0; k0 < DD; k0 += 32) {
        {
            int gm = m0 + srow;
            uint4 pk4 = make_uint4(0u, 0u, 0u, 0u);
            if (gm < M2) {
                const float* src = (gm < M1) ? (x + (size_t)gm * DD) : (xf + (size_t)(gm - M1) * DD);
                float4 a = *reinterpret_cast<const float4*>(src + k0 + seg * 8);
                float4 b = *reinterpret_cast<const float4*>(src + k0 + seg * 8 + 4);
                pk4 = make_uint4(pk2(a.x, a.y), pk2(a.z, a.w), pk2(b.x, b.y), pk2(b.z, b.w));
            }
            *reinterpret_cast<uint4*>(&As[srow * 40 + seg * 8]) = pk4;
            const float* wsrc = w + (size_t)(n0 + srow) * DD + k0 + seg * 8;
            float4 a = *reinterpret_cast<const float4*>(wsrc);
            float4 b = *reinterpret_cast<const float4*>(wsrc + 4);
            *reinterpret_cast<uint4*>(&Bs[srow * 40 + seg * 8]) =
                make_uint4(pk2(a.x, a.y), pk2(a.z, a.w), pk2(b.x, b.y), pk2(b.z, b.w));
        }
        __syncthreads();
        bf16x8 af[2], bf[2];
#pragma unroll
        for (int i = 0; i < 2; ++i)
            af[i] = *reinterpret_cast<const bf16x8*>(&As[(wm * 32 + i * 16 + r) * 40 + g * 8]);
#pragma unroll
        for (int j = 0; j < 2; ++j)
            bf[j] = *reinterpret_cast<const bf16x8*>(&Bs[(wn * 32 + j * 16 + r) * 40 + g * 8]);
#pragma unroll
        for (int i = 0; i < 2; ++i)
#pragma unroll
            for (int j = 0; j < 2; ++j)
                acc[i][j] = __builtin_amdgcn_mfma_f32_16x16x32_bf16(af[i], bf[j], acc[i][j], 0, 0, 0);
        __syncthreads();
    }

#pragma unroll
    for (int j = 0; j < 2; ++j) {
        int gn   = n0 + wn * 32 + j * 16 + r;
        float bv = bias[gn];
        int part = gn / DD;
        int dcol = gn % DD;
        int hh   = dcol / HD;
        int dd   = dcol % HD;
#pragma unroll
        for (int i = 0; i < 2; ++i) {
#pragma unroll
            for (int reg = 0; reg < 4; ++reg) {
                int gm = m0 + wm * 32 + i * 16 + g * 4 + reg;
                if (gm >= M2) continue;
                float val = acc[i][j][reg] + bv;
                int srcb = (gm >= M1) ? 1 : 0;
                int row  = gm - srcb * M1;
                int bb   = row / NN;
                int nn   = row % NN;
                uint16_t pv = f2bf(val);
                if (srcb == 0) {
                    if (part == 0)      qA[(((size_t)bb * HH + hh) * NN + nn) * HD + dd] = pv;
                    else if (part == 1) kA[(((size_t)bb * HH + hh) * NN + nn) * HD + dd] = pv;
                    else                vT[(((size_t)bb * HH + hh) * HD + dd) * NP + nn] = pv;
                } else {
                    if (part == 0)      qF[(((size_t)bb * HH + hh) * NN + nn) * HD + dd] = pv;
                    else if (part == 1) kF[(((size_t)bb * HH + hh) * NN + nn) * HD + dd] = pv;
                }
            }
        }
    }
}

// ---------------------------------------------------------------------------
// K2: softmax-1 denominators via MFMA (swapped: D[m][r] = K·Q^T). LDS-free.
// ---------------------------------------------------------------------------
__global__ __launch_bounds__(256) void k_sum1(
    const uint16_t* __restrict__ qA, const uint16_t* __restrict__ kA,
    const uint16_t* __restrict__ qF, const uint16_t* __restrict__ kF,
    float* __restrict__ Ssum)
{
    const float scale = 0.14433756729740643f; // 48^-0.5
    const int id   = blockIdx.x;
    const int b    = id & 7;
    const int rest = id >> 3;
    const int c    = rest & 31;
    const int rt   = rest >> 5;
    const int t    = threadIdx.x;
    const int lane = t & 63;
    const int wid  = t >> 6;
    const int r    = lane & 15;
    const int g    = lane >> 4;
    const int h    = c & 15;

    const uint16_t* qb = (c < 16) ? qA : qF;
    const uint16_t* kb = (c < 16) ? kA : kF;
    const size_t hb = (size_t)(b * HH + h) * NN;

    const int nq = rt * 64 + wid * 16 + r;
    bf16x8 z = {0, 0, 0, 0, 0, 0, 0, 0};
    bf16x8 qf0 = z, qf1 = z;
    if (nq < NN) {
        const uint16_t* qrow = qb + (hb + nq) * 48;
        qf0 = ldfrag(qrow + g * 8);
        if (g < 2) qf1 = ldfrag(qrow + 32 + g * 8);
    }

    float sum = 0.f;
#pragma unroll 2
    for (int mt = 0; mt < 37; ++mt) {
        const int m0 = mt * 16;
        const uint16_t* krow = kb + (hb + (size_t)(m0 + r)) * 48;  // OOB rows stay inside d_ws
        bf16x8 kf0 = ldfrag(krow + g * 8);
        bf16x8 kf1 = z;
        if (g < 2) kf1 = ldfrag(krow + 32 + g * 8);
        f32x4 d = {0.f, 0.f, 0.f, 0.f};
        d = __builtin_amdgcn_mfma_f32_16x16x32_bf16(kf0, qf0, d, 0, 0, 0);
        d = __builtin_amdgcn_mfma_f32_16x16x32_bf16(kf1, qf1, d, 0, 0, 0);
#pragma unroll
        for (int reg = 0; reg < 4; ++reg) {
            int m = m0 + g * 4 + reg;
            if (m < NN) sum += __expf(d[reg] * scale);
        }
    }
    sum += __shfl_xor(sum, 16, 64);
    sum += __shfl_xor(sum, 32, 64);
    if (g == 0 && nq < NN) Ssum[((size_t)b * CC + c) * NN + nq] = sum;
}

// ---------------------------------------------------------------------------
// K3 v5: fused scores(MFMA) -> softmax1 -> mix -> exp -> PV(MFMA).
//   m-tiles processed in PAIRS (K=32 for PV). Per pair:
//     [A(h0) sync B(h0) sync A(h1) sync B(h1) sync PV sync]
//   Phase B writes e in A-frag layout e_a[o][r][32m] (stride SRE) + denom regs.
//   Phase C: 12 MFMA/wave (4 heads x 3 d-chunks), V read direct from global
//   in transposed layout (lane=d, k=m contiguous). No V LDS tile.
// ---------------------------------------------------------------------------
__global__ __launch_bounds__(256) void k_mix_pv(
    const uint16_t* __restrict__ qA, const uint16_t* __restrict__ kA, const uint16_t* __restrict__ vT,
    const uint16_t* __restrict__ qF, const uint16_t* __restrict__ kF,
    const float* __restrict__ Ssum, const float* __restrict__ conv_w,
    float* __restrict__ weighted, float* __restrict__ pnum, float* __restrict__ pden, int NS)
{
    __shared__ uint32_t mixp32[4 * 16 * 16 * 8];           // 32 KB [wave][m][r][8u32=16o]
    __shared__ __align__(16) uint16_t e_a[16 * 16 * SRE];  // 18.4 KB e_a[o][r][32m+pad]
    __shared__ float cwL[512];                             // cwL[c][o]
    const float scale = 0.14433756729740643f;

    const int t     = threadIdx.x;
    const int id    = blockIdx.x;
    const int b     = id & 7;
    const int rest  = id >> 3;
    const int slice = rest % NS;
    const int n0    = (rest / NS) * 16;
    const int lane  = t & 63;
    const int wid   = t >> 6;
    const int r     = lane & 15;
    const int g     = lane >> 4;

    for (int i = t; i < 512; i += 256) {
        int c = i >> 4, o = i & 15;
        cwL[i] = conv_w[o * 32 + c];
    }

    float invS_r[8];
#pragma unroll
    for (int cc = 0; cc < 8; ++cc) {
        int c = wid * 8 + cc;
        int n = n0 + r;
        invS_r[cc] = (n < NN) ? 1.0f / Ssum[((size_t)b * CC + c) * NN + n] : 0.f;
    }

    const int bm = t >> 4, br = t & 15;   // phase-B thread mapping
    float dreg[16];
#pragma unroll
    for (int o = 0; o < 16; ++o) dreg[o] = 0.f;

    f32x4 pacc[4][3];
#pragma unroll
    for (int oo = 0; oo < 4; ++oo)
#pragma unroll
        for (int dc = 0; dc < 3; ++dc) pacc[oo][dc] = (f32x4){0.f, 0.f, 0.f, 0.f};

    bf16x8 z = {0, 0, 0, 0, 0, 0, 0, 0};
    const uint16_t* vTb = vT + (size_t)b * HH * HD * NP;
    __syncthreads();

    for (int mp = slice; mp < 19; mp += NS) {
#pragma unroll
        for (int half = 0; half < 2; ++half) {
            const int m0 = (mp * 2 + half) * 16;

            // ---- Phase A: QK MFMA + exp/softmax1 + partial conv mix ----
            float mixed[64];   // [o][mreg]
#pragma unroll
            for (int i = 0; i < 64; ++i) mixed[i] = 0.f;
#pragma unroll
            for (int cc = 0; cc < 8; ++cc) {
                const int c = wid * 8 + cc;
                const int h = c & 15;
                const uint16_t* qb = (c < 16) ? qA : qF;
                const uint16_t* kb = (c < 16) ? kA : kF;
                const size_t hb = (size_t)(b * HH + h) * NN;

                bf16x8 qf0 = z, qf1 = z;
                {
                    int nq = n0 + r;
                    if (nq < NN) {
                        const uint16_t* qrow = qb + (hb + nq) * 48;
                        qf0 = ldfrag(qrow + g * 8);
                        if (g < 2) qf1 = ldfrag(qrow + 32 + g * 8);
                    }
                }
                const uint16_t* krow = kb + (hb + (size_t)(m0 + r)) * 48; // OOB stays in d_ws
                bf16x8 kf0 = ldfrag(krow + g * 8);
                bf16x8 kf1 = z;
                if (g < 2) kf1 = ldfrag(krow + 32 + g * 8);

                f32x4 d = {0.f, 0.f, 0.f, 0.f};
                d = __builtin_amdgcn_mfma_f32_16x16x32_bf16(kf0, qf0, d, 0, 0, 0);
                d = __builtin_amdgcn_mfma_f32_16x16x32_bf16(kf1, qf1, d, 0, 0, 0);

                float pu[4];
#pragma unroll
                for (int reg = 0; reg < 4; ++reg)
                    pu[reg] = __expf(d[reg] * scale) * invS_r[cc];
#pragma unroll
                for (int oq = 0; oq < 4; ++oq) {
                    float4 w4 = *reinterpret_cast<const float4*>(&cwL[c * 16 + oq * 4]);
#pragma unroll
                    for (int reg = 0; reg < 4; ++reg) {
                        mixed[(oq * 4 + 0) * 4 + reg] += w4.x * pu[reg];
                        mixed[(oq * 4 + 1) * 4 + reg] += w4.y * pu[reg];
                        mixed[(oq * 4 + 2) * 4 + reg] += w4.z * pu[reg];
                        mixed[(oq * 4 + 3) * 4 + reg] += w4.w * pu[reg];
                    }
                }
            }
#pragma unroll
            for (int reg = 0; reg < 4; ++reg) {
                int base = (((wid * 16 + (g * 4 + reg)) * 16) + r) * 8;
                uint4 A0 = make_uint4(pk2(mixed[0 * 4 + reg],  mixed[1 * 4 + reg]),
                                      pk2(mixed[2 * 4 + reg],  mixed[3 * 4 + reg]),
                                      pk2(mixed[4 * 4 + reg],  mixed[5 * 4 + reg]),
                                      pk2(mixed[6 * 4 + reg],  mixed[7 * 4 + reg]));
                uint4 A1 = make_uint4(pk2(mixed[8 * 4 + reg],  mixed[9 * 4 + reg]),
                                      pk2(mixed[10 * 4 + reg], mixed[11 * 4 + reg]),
                                      pk2(mixed[12 * 4 + reg], mixed[13 * 4 + reg]),
                                      pk2(mixed[14 * 4 + reg], mixed[15 * 4 + reg]));
                *reinterpret_cast<uint4*>(&mixp32[base])     = A0;
                *reinterpret_cast<uint4*>(&mixp32[base + 4]) = A1;
            }
            __syncthreads();

            // ---- Phase B: 4-wave reduce, exp -> e_a (A-frag layout) + denom ----
            {
                float tot[16];
#pragma unroll
                for (int o = 0; o < 16; ++o) tot[o] = 0.f;
#pragma unroll
                for (int w = 0; w < 4; ++w) {
                    int base = (((w * 16 + bm) * 16) + br) * 8;
                    uint4 A0 = *reinterpret_cast<const uint4*>(&mixp32[base]);
                    uint4 A1 = *reinterpret_cast<const uint4*>(&mixp32[base + 4]);
                    tot[0]  += bf_lo(A0.x); tot[1]  += bf_hi(A0.x);
                    tot[2]  += bf_lo(A0.y); tot[3]  += bf_hi(A0.y);
                    tot[4]  += bf_lo(A0.z); tot[5]  += bf_hi(A0.z);
                    tot[6]  += bf_lo(A0.w); tot[7]  += bf_hi(A0.w);
                    tot[8]  += bf_lo(A1.x); tot[9]  += bf_hi(A1.x);
                    tot[10] += bf_lo(A1.y); tot[11] += bf_hi(A1.y);
                    tot[12] += bf_lo(A1.z); tot[13] += bf_hi(A1.z);
                    tot[14] += bf_lo(A1.w); tot[15] += bf_hi(A1.w);
                }
                bool valid = (m0 + bm) < NN;
#pragma unroll
                for (int o = 0; o < 16; ++o) {
                    float ev = valid ? __expf(tot[o]) : 0.f;
                    dreg[o] += ev;
                    e_a[(o * 16 + br) * SRE + half * 16 + bm] = f2bf(ev);
                }
            }
            __syncthreads();
        }

        // ---- Phase C: PV MFMA over this pair's 32 m ----
        {
            const int m0p = mp * 32;
#pragma unroll
            for (int oo = 0; oo < 4; ++oo) {
                int o = wid * 4 + oo;
                int ea = (o * 16 + r) * SRE + g * 8;
                uint2 lo = *reinterpret_cast<const uint2*>(&e_a[ea]);
                uint2 hi = *reinterpret_cast<const uint2*>(&e_a[ea + 4]);
                bf16x8 af = __builtin_bit_cast(bf16x8, make_uint4(lo.x, lo.y, hi.x, hi.y));
#pragma unroll
                for (int dc = 0; dc < 3; ++dc) {
                    const uint16_t* vp = vTb + ((size_t)(o * HD + dc * 16 + r)) * NP + m0p + g * 8;
                    bf16x8 bv = ldfrag(vp);
                    pacc[oo][dc] = __builtin_amdgcn_mfma_f32_16x16x32_bf16(af, bv, pacc[oo][dc], 0, 0, 0);
                }
            }
        }
        __syncthreads();
    }

    // ---- denom reduce (dreg over bm) ----
    float* dls = reinterpret_cast<float*>(mixp32);
    {
        int base = (bm * 16 + br) * 16;
#pragma unroll
        for (int o = 0; o < 16; o += 4)
            *reinterpret_cast<float4*>(&dls[base + o]) =
                make_float4(dreg[o], dreg[o + 1], dreg[o + 2], dreg[o + 3]);
    }
    __syncthreads();
    float* denl = reinterpret_cast<float*>(e_a);
    {
        const int rr = t >> 4, u = t & 15;
        float den = 0.f;
#pragma unroll
        for (int m = 0; m < 16; ++m) den += dls[(m * 16 + rr) * 16 + u];
        denl[rr * 16 + u] = den;
        if (NS > 1) {
            int n = n0 + rr;
            if (n < NN) pden[(((size_t)slice * BB + b) * NN + n) * 16 + u] = den;
        }
    }
    __syncthreads();

    // ---- writeout from PV accumulators (D: row=g*4+reg, col=r=d-in-chunk) ----
#pragma unroll
    for (int oo = 0; oo < 4; ++oo) {
        int o = wid * 4 + oo;
#pragma unroll
        for (int dc = 0; dc < 3; ++dc) {
#pragma unroll
            for (int reg = 0; reg < 4; ++reg) {
                int row = g * 4 + reg;
                int n = n0 + row;
                if (n >= NN) continue;
                float val = pacc[oo][dc][reg];
                size_t col = (size_t)o * HD + dc * 16 + r;
                if (NS == 1) {
                    weighted[((size_t)b * NN + n) * DD + col] = val / denl[row * 16 + o];
                } else {
                    pnum[(((size_t)slice * BB + b) * NN + n) * DD + col] = val;
                }
            }
        }
    }
}

// ---------------------------------------------------------------------------
// K3b: reduce slices + divide.
// ---------------------------------------------------------------------------
__global__ __launch_bounds__(256) void k_red(
    const float* __restrict__ pnum, const float* __restrict__ pden,
    float* __restrict__ weighted, int NS)
{
    int col = blockIdx.x * 256 + threadIdx.x;   // 0..767
    int bn  = blockIdx.y;                       // 0..4615
    int o   = (col * 1366) >> 16;               // col / 48
    float sn = 0.f, sd = 0.f;
    for (int s = 0; s < NS; ++s) {
        sn += pnum[((size_t)s * M1 + bn) * DD + col];
        sd += pden[((size_t)s * M1 + bn) * 16 + o];
    }
    weighted[(size_t)bn * DD + col] = sn / sd;
}

// ---------------------------------------------------------------------------
// K4: out = weighted @ proj_w^T + proj_b.  fp32 (precision headroom).
// ---------------------------------------------------------------------------
__global__ __launch_bounds__(256) void k_proj(
    const float* __restrict__ A, const float* __restrict__ w, const float* __restrict__ bias,
    float* __restrict__ out)
{
    __shared__ float As[16][65];
    __shared__ float Bs[16][65];
    const int t    = threadIdx.x;
    const int m0   = blockIdx.x * 64;
    const int n0   = blockIdx.y * 64;
    const int lrow = t >> 2;
    const int lk4  = (t & 3) << 2;
    const int tm   = (t & 15) << 2;
    const int tn   = (t >> 4) << 2;
    float acc[4][4] = {};

    for (int k0 = 0; k0 < DD; k0 += 16) {
        int gm = m0 + lrow;
        float4 av = make_float4(0.f, 0.f, 0.f, 0.f);
        if (gm < M1) av = *reinterpret_cast<const float4*>(A + (size_t)gm * DD + k0 + lk4);
        As[lk4 + 0][lrow] = av.x; As[lk4 + 1][lrow] = av.y;
        As[lk4 + 2][lrow] = av.z; As[lk4 + 3][lrow] = av.w;
        int gj = n0 + lrow;
        float4 bv = *reinterpret_cast<const float4*>(w + (size_t)gj * DD + k0 + lk4);
        Bs[lk4 + 0][lrow] = bv.x; Bs[lk4 + 1][lrow] = bv.y;
        Bs[lk4 + 2][lrow] = bv.z; Bs[lk4 + 3][lrow] = bv.w;
        __syncthreads();
#pragma unroll
        for (int k = 0; k < 16; ++k) {
            float a[4], b[4];
#pragma unroll
            for (int i = 0; i < 4; ++i) a[i] = As[k][tm + i];
#pragma unroll
            for (int j = 0; j < 4; ++j) b[j] = Bs[k][tn + j];
#pragma unroll
            for (int i = 0; i < 4; ++i)
#pragma unroll
                for (int j = 0; j < 4; ++j)
                    acc[i][j] += a[i] * b[j];
        }
        __syncthreads();
    }

#pragma unroll
    for (int i = 0; i < 4; ++i) {
        int gm = m0 + tm + i;
        if (gm >= M1) continue;
#pragma unroll
        for (int j = 0; j < 4; ++j) {
            int gn = n0 + tn + j;
            out[(size_t)gm * DD + gn] = acc[i][j] + bias[gn];
        }
    }
}

extern "C" void kernel_launch(void* const* d_in, const int* in_sizes, int n_in,
                              void* d_out, int out_size, void* d_ws, size_t ws_size,
                              hipStream_t stream) {
    const float* x      = (const float*)d_in[0];
    const float* xf     = (const float*)d_in[1];
    const float* qkv_w  = (const float*)d_in[2];
    const float* qkv_b  = (const float*)d_in[3];
    const float* conv_w = (const float*)d_in[4];
    const float* proj_w = (const float*)d_in[6];
    const float* proj_b = (const float*)d_in[7];
    float* out = (float*)d_out;

    const size_t SZ  = (size_t)BB * HH * NN * HD;   // 3,545,088 elems
    const size_t SZV = (size_t)BB * HH * HD * NP;   // 3,735,552 elems (transposed V)
    uint16_t* qA = (uint16_t*)d_ws;
    uint16_t* kA = qA + SZ;
    uint16_t* vT = kA + SZ;
    uint16_t* qF = vT + SZV;
    uint16_t* kF = qF + SZ;
    float* Ssum     = (float*)(kF + SZ);
    float* weighted = Ssum + (size_t)BB * CC * NN;
    float* pnum     = weighted + (size_t)M1 * DD;
    const size_t base_bytes  = (4 * SZ + SZV) * 2 + ((size_t)BB * CC * NN + (size_t)M1 * DD) * 4;
    const size_t slice_bytes = ((size_t)M1 * DD + (size_t)M1 * 16) * 4;
    int NS = 1;
    if (ws_size >= base_bytes + 4 * slice_bytes)      NS = 4;
    else if (ws_size >= base_bytes + 2 * slice_bytes) NS = 2;
    float* pden = pnum + (size_t)NS * M1 * DD;

    k_qkv  <<<dim3(145, 36, 1), 256, 0, stream>>>(x, xf, qkv_w, qkv_b, qA, kA, vT, qF, kF);
    k_sum1 <<<dim3(8 * 32 * 10), 256, 0, stream>>>(qA, kA, qF, kF, Ssum);
    k_mix_pv<<<dim3(8 * NS * 37), 256, 0, stream>>>(qA, kA, vT, qF, kF, Ssum, conv_w,
                                                    weighted, pnum, pden, NS);
    if (NS > 1)
        k_red<<<dim3(3, M1), 256, 0, stream>>>(pnum, pden, weighted, NS);
    k_proj <<<dim3(73, 12, 1),  256, 0, stream>>>(weighted, proj_w, proj_b, out);
}